// Round 1
// baseline (12604.324 us; speedup 1.0000x reference)
//
#include <hip/hip_runtime.h>

// ---------------------------------------------------------------------------
// Hetero GraphSAGE (2 layers) + per-type linear + edge MLP decoder, fp32.
// Sizes are fixed by the reference problem.
// ---------------------------------------------------------------------------

constexpr int NS = 100000, NT = 20000;
constexpr int E_EDGES = 800000, EL_EDGES = 200000;
constexpr int DS = 256, DT = 128, H = 256;

// ------------------------------ GEMM ---------------------------------------
// C[M,N] = A[M,K] @ W[N,K]^T (+bias) (+=C) (relu)   flags: 1=add, 2=relu
constexpr int BM = 128, BN = 128, BK = 8;

__global__ __launch_bounds__(256) void gemm_kernel(
    const float* __restrict__ A, const float* __restrict__ W,
    const float* __restrict__ bias, float* __restrict__ C,
    int M, int N, int K, int flags)
{
    __shared__ float As[BK][BM];   // [k][row]
    __shared__ float Ws[BK][BN];   // [k][col]
    const int tid = threadIdx.x;
    const int row0 = blockIdx.x * BM, col0 = blockIdx.y * BN;
    const int tx = tid & 15, ty = tid >> 4;   // 16x16 threads, 8x8 micro-tile
    const int lr = tid >> 1;                  // 0..127 staging row
    const int lk = (tid & 1) * 4;             // 0 or 4

    float acc[8][8];
#pragma unroll
    for (int i = 0; i < 8; i++)
#pragma unroll
        for (int j = 0; j < 8; j++) acc[i][j] = 0.f;

    const bool arow_ok = (row0 + lr) < M;
    const float* Ap = A + (size_t)(row0 + lr) * K + lk;
    const float* Wp = W + (size_t)(col0 + lr) * K + lk;

    for (int k0 = 0; k0 < K; k0 += BK) {
        float4 av = make_float4(0.f, 0.f, 0.f, 0.f);
        if (arow_ok) av = *(const float4*)(Ap + k0);
        float4 wv = *(const float4*)(Wp + k0);
        __syncthreads();
        As[lk + 0][lr] = av.x; As[lk + 1][lr] = av.y;
        As[lk + 2][lr] = av.z; As[lk + 3][lr] = av.w;
        Ws[lk + 0][lr] = wv.x; Ws[lk + 1][lr] = wv.y;
        Ws[lk + 2][lr] = wv.z; Ws[lk + 3][lr] = wv.w;
        __syncthreads();
#pragma unroll
        for (int k = 0; k < BK; k++) {
            float4 a0 = *(const float4*)&As[k][ty * 8];
            float4 a1 = *(const float4*)&As[k][ty * 8 + 4];
            float4 b0 = *(const float4*)&Ws[k][tx * 8];
            float4 b1 = *(const float4*)&Ws[k][tx * 8 + 4];
            float a[8] = {a0.x, a0.y, a0.z, a0.w, a1.x, a1.y, a1.z, a1.w};
            float b[8] = {b0.x, b0.y, b0.z, b0.w, b1.x, b1.y, b1.z, b1.w};
#pragma unroll
            for (int i = 0; i < 8; i++)
#pragma unroll
                for (int j = 0; j < 8; j++) acc[i][j] += a[i] * b[j];
        }
    }

    const bool do_add = flags & 1, do_relu = flags & 2;
#pragma unroll
    for (int i = 0; i < 8; i++) {
        int gr = row0 + ty * 8 + i;
        if (gr >= M) continue;
#pragma unroll
        for (int j = 0; j < 8; j += 4) {
            int gc = col0 + tx * 8 + j;
            float4 v = make_float4(acc[i][j], acc[i][j + 1], acc[i][j + 2], acc[i][j + 3]);
            if (bias) {
                v.x += bias[gc]; v.y += bias[gc + 1];
                v.z += bias[gc + 2]; v.w += bias[gc + 3];
            }
            float4* cp = (float4*)(C + (size_t)gr * N + gc);
            if (do_add) {
                float4 o = *cp;
                v.x += o.x; v.y += o.y; v.z += o.z; v.w += o.w;
            }
            if (do_relu) {
                v.x = fmaxf(v.x, 0.f); v.y = fmaxf(v.y, 0.f);
                v.z = fmaxf(v.z, 0.f); v.w = fmaxf(v.w, 0.f);
            }
            *cp = v;
        }
    }
}

// --------------------------- degree counts ---------------------------------
__global__ void count_kernel(const int* __restrict__ src, const int* __restrict__ dst,
                             float* __restrict__ cnt_src, float* __restrict__ cnt_dst, int E)
{
    int e = blockIdx.x * blockDim.x + threadIdx.x;
    if (e < E) {
        atomicAdd(&cnt_src[src[e]], 1.f);
        atomicAdd(&cnt_dst[dst[e]], 1.f);
    }
}

// -------------------------- scatter-sum ------------------------------------
// out[sidx[e]][:] += X[gidx[e]][:] ; one thread per 4 floats; D = 1<<(logper+2)
__global__ void scatter_kernel(const float* __restrict__ X, const int* __restrict__ gidx,
                               const int* __restrict__ sidx, float* __restrict__ out,
                               int E, int D, int logper)
{
    long long tid = (long long)blockIdx.x * blockDim.x + threadIdx.x;
    int per = D >> 2;
    long long total = (long long)E * per;
    if (tid >= total) return;
    int e = (int)(tid >> logper);
    int c = (int)(tid & (per - 1));
    const float4 v = *(const float4*)&X[(size_t)gidx[e] * D + 4 * c];
    float* o = &out[(size_t)sidx[e] * D + 4 * c];
    atomicAdd(o + 0, v.x); atomicAdd(o + 1, v.y);
    atomicAdd(o + 2, v.z); atomicAdd(o + 3, v.w);
}

// ------------------------- divide by count ---------------------------------
__global__ void divcnt_kernel(float* __restrict__ m, const float* __restrict__ cnt,
                              int N, int D, int logper)
{
    long long tid = (long long)blockIdx.x * blockDim.x + threadIdx.x;
    int per = D >> 2;
    long long total = (long long)N * per;
    if (tid >= total) return;
    int n = (int)(tid >> logper);
    int c = (int)(tid & (per - 1));
    float d = fmaxf(cnt[n], 1.f);
    float4* p = (float4*)&m[(size_t)n * D + 4 * c];
    float4 v = *p;
    v.x /= d; v.y /= d; v.z /= d; v.w /= d;
    *p = v;
}

// ----------------------------- decoder -------------------------------------
// out[e] = Wd2 . relu(Wd1 @ concat(z_s[ls[e]], z_t[ld[e]]) + bd1) + bd2
constexpr int DE = 16;  // edges per block

__global__ __launch_bounds__(256) void decoder_kernel(
    const float* __restrict__ z_s, const float* __restrict__ z_t,
    const int* __restrict__ ls, const int* __restrict__ ld,
    const float* __restrict__ Wd1, const float* __restrict__ bd1,
    const float* __restrict__ Wd2, const float* __restrict__ bd2,
    float* __restrict__ out, int EL)
{
    __shared__ float zT[512 * DE];     // [k][e], stride 16
    __shared__ float wT[32 * 260];     // [k][j], stride 260 (also reused for reduction)
    const int tid = threadIdx.x;
    const int e0 = blockIdx.x * DE;

    // stage z (transposed)
    for (int idx = tid; idx < DE * 512; idx += 256) {
        int e = idx >> 9, k = idx & 511;
        int ge = e0 + e;
        float v = 0.f;
        if (ge < EL)
            v = (k < 256) ? z_s[(size_t)ls[ge] * 256 + k]
                          : z_t[(size_t)ld[ge] * 256 + (k - 256)];
        zT[k * DE + e] = v;
    }

    const int te = tid >> 6;   // 0..3  -> edges 4*te..4*te+3
    const int tj = tid & 63;   // 0..63 -> hidden 4*tj..4*tj+3
    float acc[4][4];
#pragma unroll
    for (int i = 0; i < 4; i++)
#pragma unroll
        for (int j = 0; j < 4; j++) acc[i][j] = 0.f;

    for (int k0 = 0; k0 < 512; k0 += 32) {
        __syncthreads();   // also covers initial zT staging; protects wT reuse
        for (int idx = tid; idx < 32 * 256; idx += 256) {
            int j = idx >> 5, k = idx & 31;
            wT[k * 260 + j] = Wd1[(size_t)j * 512 + k0 + k];
        }
        __syncthreads();
#pragma unroll
        for (int k = 0; k < 32; k++) {
            float4 b = *(const float4*)&wT[k * 260 + 4 * tj];
            float4 a = *(const float4*)&zT[(k0 + k) * DE + 4 * te];
            float av[4] = {a.x, a.y, a.z, a.w};
            float bv[4] = {b.x, b.y, b.z, b.w};
#pragma unroll
            for (int i = 0; i < 4; i++)
#pragma unroll
                for (int j = 0; j < 4; j++) acc[i][j] += av[i] * bv[j];
        }
    }

    __syncthreads();           // done reading wT; reuse as reduction buffer
    float* red = wT;           // [e][j], stride 257
#pragma unroll
    for (int i = 0; i < 4; i++) {
#pragma unroll
        for (int j = 0; j < 4; j++) {
            int gj = 4 * tj + j;
            float h = fmaxf(acc[i][j] + bd1[gj], 0.f);
            red[(4 * te + i) * 257 + gj] = Wd2[gj] * h;
        }
    }
    __syncthreads();
    {   // partial reduce: 16 threads per edge
        int e = tid >> 4, i = tid & 15;
        float s = 0.f;
#pragma unroll
        for (int t = 0; t < 16; t++) s += red[e * 257 + i * 16 + t];
        zT[e * 16 + i] = s;
    }
    __syncthreads();
    if (tid < DE) {
        float s2 = 0.f;
#pragma unroll
        for (int t = 0; t < 16; t++) s2 += zT[tid * 16 + t];
        int ge = e0 + tid;
        if (ge < EL) out[ge] = s2 + bd2[0];
    }
}

// ---------------------------------------------------------------------------
extern "C" void kernel_launch(void* const* d_in, const int* in_sizes, int n_in,
                              void* d_out, int out_size, void* d_ws, size_t ws_size,
                              hipStream_t stream)
{
    const float* x_sotu  = (const float*)d_in[0];
    const float* x_taxon = (const float*)d_in[1];
    const int* edge_src  = (const int*)d_in[2];
    const int* edge_dst  = (const int*)d_in[3];
    const int* label_src = (const int*)d_in[4];
    const int* label_dst = (const int*)d_in[5];
    const float* Wl1_st = (const float*)d_in[6];
    const float* bl1_st = (const float*)d_in[7];
    const float* Wr1_st = (const float*)d_in[8];
    const float* Wl1_ts = (const float*)d_in[9];
    const float* bl1_ts = (const float*)d_in[10];
    const float* Wr1_ts = (const float*)d_in[11];
    const float* Wl2_st = (const float*)d_in[12];
    const float* bl2_st = (const float*)d_in[13];
    const float* Wr2_st = (const float*)d_in[14];
    const float* Wl2_ts = (const float*)d_in[15];
    const float* bl2_ts = (const float*)d_in[16];
    const float* Wr2_ts = (const float*)d_in[17];
    const float* Wlin_s = (const float*)d_in[18];
    const float* blin_s = (const float*)d_in[19];
    const float* Wlin_t = (const float*)d_in[20];
    const float* blin_t = (const float*)d_in[21];
    const float* Wd1 = (const float*)d_in[22];
    const float* bd1 = (const float*)d_in[23];
    const float* Wd2 = (const float*)d_in[24];
    const float* bd2 = (const float*)d_in[25];

    // -------- workspace layout (floats) --------
    float* ws = (float*)d_ws;
    size_t o = 0;
    float* cnt_s = ws + o; o += NS;
    float* cnt_t = ws + o; o += NT;
    float* m_s  = ws + o; o += (size_t)NS * H;   // layer1 uses [NS][128] compact
    float* m_t  = ws + o; o += (size_t)NT * H;
    float* h1_s = ws + o; o += (size_t)NS * H;
    float* h1_t = ws + o; o += (size_t)NT * H;
    float* h2_s = ws + o; o += (size_t)NS * H;
    float* h2_t = ws + o; o += (size_t)NT * H;
    float* z_s = m_s;   // reuse (messages dead by then)
    float* z_t = m_t;

    const dim3 blk(256);
    auto grd = [](int M) { return dim3((M + BM - 1) / BM, H / BN); };

    // zero counts + layer-1 message buffers (contiguous region)
    hipMemsetAsync(cnt_s, 0,
                   (size_t)(NS + NT + (size_t)NS * H + (size_t)NT * H) * sizeof(float),
                   stream);

    count_kernel<<<(E_EDGES + 255) / 256, blk, 0, stream>>>(edge_src, edge_dst,
                                                            cnt_s, cnt_t, E_EDGES);

    // ---- layer 1 aggregation ----
    {
        long long tot = (long long)E_EDGES * (DS / 4);
        scatter_kernel<<<(int)((tot + 255) / 256), blk, 0, stream>>>(
            x_sotu, edge_src, edge_dst, m_t, E_EDGES, DS, 6);
        tot = (long long)E_EDGES * (DT / 4);
        scatter_kernel<<<(int)((tot + 255) / 256), blk, 0, stream>>>(
            x_taxon, edge_dst, edge_src, m_s, E_EDGES, DT, 5);
    }
    divcnt_kernel<<<(NT * (DS / 4) + 255) / 256, blk, 0, stream>>>(m_t, cnt_t, NT, DS, 6);
    divcnt_kernel<<<(NS * (DT / 4) + 255) / 256, blk, 0, stream>>>(m_s, cnt_s, NS, DT, 5);

    // ---- layer 1 GEMMs ----
    gemm_kernel<<<grd(NT), blk, 0, stream>>>(m_t, Wl1_st, bl1_st, h1_t, NT, H, 256, 0);
    gemm_kernel<<<grd(NT), blk, 0, stream>>>(x_taxon, Wr1_st, nullptr, h1_t, NT, H, 128, 3);
    gemm_kernel<<<grd(NS), blk, 0, stream>>>(m_s, Wl1_ts, bl1_ts, h1_s, NS, H, 128, 0);
    gemm_kernel<<<grd(NS), blk, 0, stream>>>(x_sotu, Wr1_ts, nullptr, h1_s, NS, H, 256, 3);

    // ---- layer 2 aggregation ----
    hipMemsetAsync(m_s, 0, ((size_t)NS * H + (size_t)NT * H) * sizeof(float), stream);
    {
        long long tot = (long long)E_EDGES * (H / 4);
        scatter_kernel<<<(int)((tot + 255) / 256), blk, 0, stream>>>(
            h1_s, edge_src, edge_dst, m_t, E_EDGES, H, 6);
        scatter_kernel<<<(int)((tot + 255) / 256), blk, 0, stream>>>(
            h1_t, edge_dst, edge_src, m_s, E_EDGES, H, 6);
    }
    divcnt_kernel<<<(NT * (H / 4) + 255) / 256, blk, 0, stream>>>(m_t, cnt_t, NT, H, 6);
    divcnt_kernel<<<(NS * (H / 4) + 255) / 256, blk, 0, stream>>>(m_s, cnt_s, NS, H, 6);

    // ---- layer 2 GEMMs ----
    gemm_kernel<<<grd(NT), blk, 0, stream>>>(m_t, Wl2_st, bl2_st, h2_t, NT, H, 256, 0);
    gemm_kernel<<<grd(NT), blk, 0, stream>>>(h1_t, Wr2_st, nullptr, h2_t, NT, H, 256, 3);
    gemm_kernel<<<grd(NS), blk, 0, stream>>>(m_s, Wl2_ts, bl2_ts, h2_s, NS, H, 256, 0);
    gemm_kernel<<<grd(NS), blk, 0, stream>>>(h1_s, Wr2_ts, nullptr, h2_s, NS, H, 256, 3);

    // ---- per-type projection ----
    gemm_kernel<<<grd(NS), blk, 0, stream>>>(h2_s, Wlin_s, blin_s, z_s, NS, H, 256, 0);
    gemm_kernel<<<grd(NT), blk, 0, stream>>>(h2_t, Wlin_t, blin_t, z_t, NT, H, 256, 0);

    // ---- fused edge decoder ----
    decoder_kernel<<<(EL_EDGES + DE - 1) / DE, blk, 0, stream>>>(
        z_s, z_t, label_src, label_dst, Wd1, bd1, Wd2, bd2,
        (float*)d_out, EL_EDGES);
}

// Round 2
// 3592.728 us; speedup vs baseline: 3.5083x; 3.5083x over previous
//
#include <hip/hip_runtime.h>

// ---------------------------------------------------------------------------
// Hetero GraphSAGE (2 layers) + per-type linear + edge MLP decoder, fp32.
// R1: replace atomic scatter-sum (3.28 GB WRITE_SIZE/dispatch, 9.4ms total)
//     with per-call CSR build + register-accumulating gather (no float atomics).
// ---------------------------------------------------------------------------

constexpr int NS = 100000, NT = 20000;
constexpr int E_EDGES = 800000, EL_EDGES = 200000;
constexpr int DS = 256, DT = 128, H = 256;

// ------------------------------ GEMM ---------------------------------------
// C[M,N] = A[M,K] @ W[N,K]^T (+bias) (+=C) (relu)   flags: 1=add, 2=relu
constexpr int BM = 128, BN = 128, BK = 8;

__global__ __launch_bounds__(256) void gemm_kernel(
    const float* __restrict__ A, const float* __restrict__ W,
    const float* __restrict__ bias, float* __restrict__ C,
    int M, int N, int K, int flags)
{
    __shared__ float As[BK][BM];   // [k][row]
    __shared__ float Ws[BK][BN];   // [k][col]
    const int tid = threadIdx.x;
    const int row0 = blockIdx.x * BM, col0 = blockIdx.y * BN;
    const int tx = tid & 15, ty = tid >> 4;   // 16x16 threads, 8x8 micro-tile
    const int lr = tid >> 1;                  // 0..127 staging row
    const int lk = (tid & 1) * 4;             // 0 or 4

    float acc[8][8];
#pragma unroll
    for (int i = 0; i < 8; i++)
#pragma unroll
        for (int j = 0; j < 8; j++) acc[i][j] = 0.f;

    const bool arow_ok = (row0 + lr) < M;
    const float* Ap = A + (size_t)(row0 + lr) * K + lk;
    const float* Wp = W + (size_t)(col0 + lr) * K + lk;

    for (int k0 = 0; k0 < K; k0 += BK) {
        float4 av = make_float4(0.f, 0.f, 0.f, 0.f);
        if (arow_ok) av = *(const float4*)(Ap + k0);
        float4 wv = *(const float4*)(Wp + k0);
        __syncthreads();
        As[lk + 0][lr] = av.x; As[lk + 1][lr] = av.y;
        As[lk + 2][lr] = av.z; As[lk + 3][lr] = av.w;
        Ws[lk + 0][lr] = wv.x; Ws[lk + 1][lr] = wv.y;
        Ws[lk + 2][lr] = wv.z; Ws[lk + 3][lr] = wv.w;
        __syncthreads();
#pragma unroll
        for (int k = 0; k < BK; k++) {
            float4 a0 = *(const float4*)&As[k][ty * 8];
            float4 a1 = *(const float4*)&As[k][ty * 8 + 4];
            float4 b0 = *(const float4*)&Ws[k][tx * 8];
            float4 b1 = *(const float4*)&Ws[k][tx * 8 + 4];
            float a[8] = {a0.x, a0.y, a0.z, a0.w, a1.x, a1.y, a1.z, a1.w};
            float b[8] = {b0.x, b0.y, b0.z, b0.w, b1.x, b1.y, b1.z, b1.w};
#pragma unroll
            for (int i = 0; i < 8; i++)
#pragma unroll
                for (int j = 0; j < 8; j++) acc[i][j] += a[i] * b[j];
        }
    }

    const bool do_add = flags & 1, do_relu = flags & 2;
#pragma unroll
    for (int i = 0; i < 8; i++) {
        int gr = row0 + ty * 8 + i;
        if (gr >= M) continue;
#pragma unroll
        for (int j = 0; j < 8; j += 4) {
            int gc = col0 + tx * 8 + j;
            float4 v = make_float4(acc[i][j], acc[i][j + 1], acc[i][j + 2], acc[i][j + 3]);
            if (bias) {
                v.x += bias[gc]; v.y += bias[gc + 1];
                v.z += bias[gc + 2]; v.w += bias[gc + 3];
            }
            float4* cp = (float4*)(C + (size_t)gr * N + gc);
            if (do_add) {
                float4 o = *cp;
                v.x += o.x; v.y += o.y; v.z += o.z; v.w += o.w;
            }
            if (do_relu) {
                v.x = fmaxf(v.x, 0.f); v.y = fmaxf(v.y, 0.f);
                v.z = fmaxf(v.z, 0.f); v.w = fmaxf(v.w, 0.f);
            }
            *cp = v;
        }
    }
}

// --------------------------- CSR build -------------------------------------
__global__ void count_kernel(const int* __restrict__ src, const int* __restrict__ dst,
                             int* __restrict__ cnt_s, int* __restrict__ cnt_t, int E)
{
    int e = blockIdx.x * blockDim.x + threadIdx.x;
    if (e < E) {
        atomicAdd(&cnt_s[src[e]], 1);
        atomicAdd(&cnt_t[dst[e]], 1);
    }
}

// per-block (1024-elem) sums
__global__ __launch_bounds__(256) void partial_sum_kernel(
    const int* __restrict__ cnt, int* __restrict__ bsum, int N)
{
    __shared__ int sdata[256];
    const int t = threadIdx.x;
    const int base = blockIdx.x * 1024;
    int s = 0;
    for (int i = t; i < 1024; i += 256) {
        int idx = base + i;
        s += (idx < N) ? cnt[idx] : 0;
    }
    sdata[t] = s; __syncthreads();
    for (int off = 128; off > 0; off >>= 1) {
        if (t < off) sdata[t] += sdata[t + off];
        __syncthreads();
    }
    if (t == 0) bsum[blockIdx.x] = sdata[0];
}

// exclusive scan of block sums (nb <= 128, single thread is fine)
__global__ void scan_bsum_kernel(int* __restrict__ bsum, int nb)
{
    if (blockIdx.x == 0 && threadIdx.x == 0) {
        int run = 0;
        for (int i = 0; i < nb; i++) { int v = bsum[i]; bsum[i] = run; run += v; }
    }
}

// per-block exclusive scan + block offset -> rowptr[N+1]
__global__ __launch_bounds__(256) void scan_block_kernel(
    const int* __restrict__ cnt, const int* __restrict__ bsum,
    int* __restrict__ rowptr, int N)
{
    __shared__ int sc[256];
    const int t = threadIdx.x;
    const int base = blockIdx.x * 1024 + t * 4;
    int v[4]; int s = 0;
#pragma unroll
    for (int j = 0; j < 4; j++) {
        int idx = base + j;
        v[j] = (idx < N) ? cnt[idx] : 0;
        s += v[j];
    }
    sc[t] = s; __syncthreads();
    for (int off = 1; off < 256; off <<= 1) {
        int add = (t >= off) ? sc[t - off] : 0;
        __syncthreads();
        sc[t] += add;
        __syncthreads();
    }
    int excl = sc[t] - s + bsum[blockIdx.x];
#pragma unroll
    for (int j = 0; j < 4; j++) {
        int idx = base + j;
        if (idx < N) rowptr[idx] = excl;
        if (idx == N - 1) rowptr[N] = excl + v[j];
        excl += v[j];
    }
}

__global__ void copy_int_kernel(const int* __restrict__ a, int* __restrict__ b, int n)
{
    int i = blockIdx.x * blockDim.x + threadIdx.x;
    if (i < n) b[i] = a[i];
}

// fill neighbor lists via atomic cursors (cursor pre-initialized to rowptr)
__global__ void fill_kernel(const int* __restrict__ src, const int* __restrict__ dst,
                            int* __restrict__ cur_s, int* __restrict__ cur_t,
                            int* __restrict__ col_s, int* __restrict__ col_t, int E)
{
    int e = blockIdx.x * blockDim.x + threadIdx.x;
    if (e < E) {
        int s = src[e], d = dst[e];
        int pt = atomicAdd(&cur_t[d], 1);
        col_t[pt] = s;
        int ps = atomicAdd(&cur_s[s], 1);
        col_s[ps] = d;
    }
}

// ----------------------- gather mean aggregation ---------------------------
// out[n][:] = mean_{i in rowptr[n]..rowptr[n+1]} X[col[i]][:]
// D/4 threads per node; 256-thread blocks.
__global__ __launch_bounds__(256) void gather_mean_kernel(
    const float* __restrict__ X, const int* __restrict__ rowptr,
    const int* __restrict__ col, float* __restrict__ out, int N, int D)
{
    const int tpn = D >> 2;                    // threads per node (64 or 32)
    const int npb = 256 / tpn;                 // nodes per block
    const int node = blockIdx.x * npb + threadIdx.x / tpn;
    const int c = (threadIdx.x % tpn) * 4;
    if (node >= N) return;
    const int beg = rowptr[node], end = rowptr[node + 1];
    float4 acc0 = make_float4(0.f, 0.f, 0.f, 0.f);
    float4 acc1 = make_float4(0.f, 0.f, 0.f, 0.f);
    int i = beg;
    for (; i + 1 < end; i += 2) {
        int n0 = col[i], n1 = col[i + 1];
        float4 v0 = *(const float4*)&X[(size_t)n0 * D + c];
        float4 v1 = *(const float4*)&X[(size_t)n1 * D + c];
        acc0.x += v0.x; acc0.y += v0.y; acc0.z += v0.z; acc0.w += v0.w;
        acc1.x += v1.x; acc1.y += v1.y; acc1.z += v1.z; acc1.w += v1.w;
    }
    if (i < end) {
        float4 v0 = *(const float4*)&X[(size_t)col[i] * D + c];
        acc0.x += v0.x; acc0.y += v0.y; acc0.z += v0.z; acc0.w += v0.w;
    }
    float inv = 1.f / fmaxf((float)(end - beg), 1.f);
    float4 r;
    r.x = (acc0.x + acc1.x) * inv; r.y = (acc0.y + acc1.y) * inv;
    r.z = (acc0.z + acc1.z) * inv; r.w = (acc0.w + acc1.w) * inv;
    *(float4*)&out[(size_t)node * D + c] = r;
}

// ----------------------------- decoder -------------------------------------
// out[e] = Wd2 . relu(Wd1 @ concat(z_s[ls[e]], z_t[ld[e]]) + bd1) + bd2
constexpr int DE = 16;  // edges per block

__global__ __launch_bounds__(256) void decoder_kernel(
    const float* __restrict__ z_s, const float* __restrict__ z_t,
    const int* __restrict__ ls, const int* __restrict__ ld,
    const float* __restrict__ Wd1, const float* __restrict__ bd1,
    const float* __restrict__ Wd2, const float* __restrict__ bd2,
    float* __restrict__ out, int EL)
{
    __shared__ float zT[512 * DE];     // [k][e], stride 16
    __shared__ float wT[32 * 260];     // [k][j], stride 260 (also reused for reduction)
    const int tid = threadIdx.x;
    const int e0 = blockIdx.x * DE;

    // stage z (transposed)
    for (int idx = tid; idx < DE * 512; idx += 256) {
        int e = idx >> 9, k = idx & 511;
        int ge = e0 + e;
        float v = 0.f;
        if (ge < EL)
            v = (k < 256) ? z_s[(size_t)ls[ge] * 256 + k]
                          : z_t[(size_t)ld[ge] * 256 + (k - 256)];
        zT[k * DE + e] = v;
    }

    const int te = tid >> 6;   // 0..3  -> edges 4*te..4*te+3
    const int tj = tid & 63;   // 0..63 -> hidden 4*tj..4*tj+3
    float acc[4][4];
#pragma unroll
    for (int i = 0; i < 4; i++)
#pragma unroll
        for (int j = 0; j < 4; j++) acc[i][j] = 0.f;

    for (int k0 = 0; k0 < 512; k0 += 32) {
        __syncthreads();   // also covers initial zT staging; protects wT reuse
        for (int idx = tid; idx < 32 * 256; idx += 256) {
            int j = idx >> 5, k = idx & 31;
            wT[k * 260 + j] = Wd1[(size_t)j * 512 + k0 + k];
        }
        __syncthreads();
#pragma unroll
        for (int k = 0; k < 32; k++) {
            float4 b = *(const float4*)&wT[k * 260 + 4 * tj];
            float4 a = *(const float4*)&zT[(k0 + k) * DE + 4 * te];
            float av[4] = {a.x, a.y, a.z, a.w};
            float bv[4] = {b.x, b.y, b.z, b.w};
#pragma unroll
            for (int i = 0; i < 4; i++)
#pragma unroll
                for (int j = 0; j < 4; j++) acc[i][j] += av[i] * bv[j];
        }
    }

    __syncthreads();           // done reading wT; reuse as reduction buffer
    float* red = wT;           // [e][j], stride 257
#pragma unroll
    for (int i = 0; i < 4; i++) {
#pragma unroll
        for (int j = 0; j < 4; j++) {
            int gj = 4 * tj + j;
            float h = fmaxf(acc[i][j] + bd1[gj], 0.f);
            red[(4 * te + i) * 257 + gj] = Wd2[gj] * h;
        }
    }
    __syncthreads();
    {   // partial reduce: 16 threads per edge
        int e = tid >> 4, i = tid & 15;
        float s = 0.f;
#pragma unroll
        for (int t = 0; t < 16; t++) s += red[e * 257 + i * 16 + t];
        zT[e * 16 + i] = s;
    }
    __syncthreads();
    if (tid < DE) {
        float s2 = 0.f;
#pragma unroll
        for (int t = 0; t < 16; t++) s2 += zT[tid * 16 + t];
        int ge = e0 + tid;
        if (ge < EL) out[ge] = s2 + bd2[0];
    }
}

// ---------------------------------------------------------------------------
extern "C" void kernel_launch(void* const* d_in, const int* in_sizes, int n_in,
                              void* d_out, int out_size, void* d_ws, size_t ws_size,
                              hipStream_t stream)
{
    const float* x_sotu  = (const float*)d_in[0];
    const float* x_taxon = (const float*)d_in[1];
    const int* edge_src  = (const int*)d_in[2];
    const int* edge_dst  = (const int*)d_in[3];
    const int* label_src = (const int*)d_in[4];
    const int* label_dst = (const int*)d_in[5];
    const float* Wl1_st = (const float*)d_in[6];
    const float* bl1_st = (const float*)d_in[7];
    const float* Wr1_st = (const float*)d_in[8];
    const float* Wl1_ts = (const float*)d_in[9];
    const float* bl1_ts = (const float*)d_in[10];
    const float* Wr1_ts = (const float*)d_in[11];
    const float* Wl2_st = (const float*)d_in[12];
    const float* bl2_st = (const float*)d_in[13];
    const float* Wr2_st = (const float*)d_in[14];
    const float* Wl2_ts = (const float*)d_in[15];
    const float* bl2_ts = (const float*)d_in[16];
    const float* Wr2_ts = (const float*)d_in[17];
    const float* Wlin_s = (const float*)d_in[18];
    const float* blin_s = (const float*)d_in[19];
    const float* Wlin_t = (const float*)d_in[20];
    const float* blin_t = (const float*)d_in[21];
    const float* Wd1 = (const float*)d_in[22];
    const float* bd1 = (const float*)d_in[23];
    const float* Wd2 = (const float*)d_in[24];
    const float* bd2 = (const float*)d_in[25];

    // -------- workspace layout --------
    // int region first
    int* wi = (int*)d_ws;
    size_t io = 0;
    int* cnt_s   = wi + io; io += NS;
    int* cnt_t   = wi + io; io += NT;
    int* rowptr_s = wi + io; io += NS + 4;     // padded for alignment
    int* rowptr_t = wi + io; io += NT + 4;
    int* cur_s   = wi + io; io += NS;
    int* cur_t   = wi + io; io += NT;
    int* col_s   = wi + io; io += E_EDGES;     // taxon idx per sotu-side slot
    int* col_t   = wi + io; io += E_EDGES;     // sotu idx per taxon-side slot
    int* bsum_s  = wi + io; io += 128;
    int* bsum_t  = wi + io; io += 128;
    io = (io + 3) & ~(size_t)3;                // 16B-align float region

    float* ws = (float*)(wi + io);
    size_t o = 0;
    float* m_s  = ws + o; o += (size_t)NS * H;   // layer1 uses [NS][128] compact
    float* m_t  = ws + o; o += (size_t)NT * H;
    float* h1_s = ws + o; o += (size_t)NS * H;
    float* h1_t = ws + o; o += (size_t)NT * H;
    float* h2_s = ws + o; o += (size_t)NS * H;
    float* h2_t = ws + o; o += (size_t)NT * H;
    float* z_s = m_s;   // reuse (messages dead by then)
    float* z_t = m_t;

    const dim3 blk(256);
    auto grd = [](int M) { return dim3((M + BM - 1) / BM, H / BN); };
    const int nbS = (NS + 1023) / 1024;   // 98
    const int nbT = (NT + 1023) / 1024;   // 20

    // ---- CSR build (both directions) ----
    hipMemsetAsync(cnt_s, 0, (size_t)(NS + NT) * sizeof(int), stream);
    count_kernel<<<(E_EDGES + 255) / 256, blk, 0, stream>>>(edge_src, edge_dst,
                                                            cnt_s, cnt_t, E_EDGES);
    partial_sum_kernel<<<nbS, blk, 0, stream>>>(cnt_s, bsum_s, NS);
    partial_sum_kernel<<<nbT, blk, 0, stream>>>(cnt_t, bsum_t, NT);
    scan_bsum_kernel<<<1, 64, 0, stream>>>(bsum_s, nbS);
    scan_bsum_kernel<<<1, 64, 0, stream>>>(bsum_t, nbT);
    scan_block_kernel<<<nbS, blk, 0, stream>>>(cnt_s, bsum_s, rowptr_s, NS);
    scan_block_kernel<<<nbT, blk, 0, stream>>>(cnt_t, bsum_t, rowptr_t, NT);
    copy_int_kernel<<<(NS + 255) / 256, blk, 0, stream>>>(rowptr_s, cur_s, NS);
    copy_int_kernel<<<(NT + 255) / 256, blk, 0, stream>>>(rowptr_t, cur_t, NT);
    fill_kernel<<<(E_EDGES + 255) / 256, blk, 0, stream>>>(
        edge_src, edge_dst, cur_s, cur_t, col_s, col_t, E_EDGES);

    // ---- layer 1 aggregation (gather, mean fused) ----
    gather_mean_kernel<<<(NT * 64 + 255) / 256, blk, 0, stream>>>(
        x_sotu, rowptr_t, col_t, m_t, NT, DS);            // taxon <- mean(x_sotu)
    gather_mean_kernel<<<(NS * 32 + 255) / 256, blk, 0, stream>>>(
        x_taxon, rowptr_s, col_s, m_s, NS, DT);           // sotu <- mean(x_taxon)

    // ---- layer 1 GEMMs ----
    gemm_kernel<<<grd(NT), blk, 0, stream>>>(m_t, Wl1_st, bl1_st, h1_t, NT, H, 256, 0);
    gemm_kernel<<<grd(NT), blk, 0, stream>>>(x_taxon, Wr1_st, nullptr, h1_t, NT, H, 128, 3);
    gemm_kernel<<<grd(NS), blk, 0, stream>>>(m_s, Wl1_ts, bl1_ts, h1_s, NS, H, 128, 0);
    gemm_kernel<<<grd(NS), blk, 0, stream>>>(x_sotu, Wr1_ts, nullptr, h1_s, NS, H, 256, 3);

    // ---- layer 2 aggregation ----
    gather_mean_kernel<<<(NT * 64 + 255) / 256, blk, 0, stream>>>(
        h1_s, rowptr_t, col_t, m_t, NT, H);
    gather_mean_kernel<<<(NS * 64 + 255) / 256, blk, 0, stream>>>(
        h1_t, rowptr_s, col_s, m_s, NS, H);

    // ---- layer 2 GEMMs ----
    gemm_kernel<<<grd(NT), blk, 0, stream>>>(m_t, Wl2_st, bl2_st, h2_t, NT, H, 256, 0);
    gemm_kernel<<<grd(NT), blk, 0, stream>>>(h1_t, Wr2_st, nullptr, h2_t, NT, H, 256, 3);
    gemm_kernel<<<grd(NS), blk, 0, stream>>>(m_s, Wl2_ts, bl2_ts, h2_s, NS, H, 256, 0);
    gemm_kernel<<<grd(NS), blk, 0, stream>>>(h1_s, Wr2_ts, nullptr, h2_s, NS, H, 256, 3);

    // ---- per-type projection ----
    gemm_kernel<<<grd(NS), blk, 0, stream>>>(h2_s, Wlin_s, blin_s, z_s, NS, H, 256, 0);
    gemm_kernel<<<grd(NT), blk, 0, stream>>>(h2_t, Wlin_t, blin_t, z_t, NT, H, 256, 0);

    // ---- fused edge decoder ----
    decoder_kernel<<<(EL_EDGES + DE - 1) / DE, blk, 0, stream>>>(
        z_s, z_t, label_src, label_dst, Wd1, bd1, Wd2, bd2,
        (float*)d_out, EL_EDGES);
}

// Round 3
// 2548.477 us; speedup vs baseline: 4.9458x; 1.4098x over previous
//
#include <hip/hip_runtime.h>

// ---------------------------------------------------------------------------
// Hetero GraphSAGE (2 layers) + per-type linear + edge MLP decoder, fp32.
// R1: CSR-gather aggregation (killed 3.28GB/dispatch atomic write-through).
// R2: decoder rewritten as register-blocked GEMM (64 edges x 256 hid, BK=32,
//     8x8 micro-tile) with conflict-engineered LDS + shfl-reduce epilogue.
//     Old decoder had 2.16e8 LDS bank-conflict cycles (32-way on zT stores).
// ---------------------------------------------------------------------------

constexpr int NS = 100000, NT = 20000;
constexpr int E_EDGES = 800000, EL_EDGES = 200000;
constexpr int DS = 256, DT = 128, H = 256;

// ------------------------------ GEMM ---------------------------------------
// C[M,N] = A[M,K] @ W[N,K]^T (+bias) (+=C) (relu)   flags: 1=add, 2=relu
constexpr int BM = 128, BN = 128, BK = 8;

__global__ __launch_bounds__(256) void gemm_kernel(
    const float* __restrict__ A, const float* __restrict__ W,
    const float* __restrict__ bias, float* __restrict__ C,
    int M, int N, int K, int flags)
{
    __shared__ float As[BK][BM];   // [k][row]
    __shared__ float Ws[BK][BN];   // [k][col]
    const int tid = threadIdx.x;
    const int row0 = blockIdx.x * BM, col0 = blockIdx.y * BN;
    const int tx = tid & 15, ty = tid >> 4;   // 16x16 threads, 8x8 micro-tile
    const int lr = tid >> 1;                  // 0..127 staging row
    const int lk = (tid & 1) * 4;             // 0 or 4

    float acc[8][8];
#pragma unroll
    for (int i = 0; i < 8; i++)
#pragma unroll
        for (int j = 0; j < 8; j++) acc[i][j] = 0.f;

    const bool arow_ok = (row0 + lr) < M;
    const float* Ap = A + (size_t)(row0 + lr) * K + lk;
    const float* Wp = W + (size_t)(col0 + lr) * K + lk;

    for (int k0 = 0; k0 < K; k0 += BK) {
        float4 av = make_float4(0.f, 0.f, 0.f, 0.f);
        if (arow_ok) av = *(const float4*)(Ap + k0);
        float4 wv = *(const float4*)(Wp + k0);
        __syncthreads();
        As[lk + 0][lr] = av.x; As[lk + 1][lr] = av.y;
        As[lk + 2][lr] = av.z; As[lk + 3][lr] = av.w;
        Ws[lk + 0][lr] = wv.x; Ws[lk + 1][lr] = wv.y;
        Ws[lk + 2][lr] = wv.z; Ws[lk + 3][lr] = wv.w;
        __syncthreads();
#pragma unroll
        for (int k = 0; k < BK; k++) {
            float4 a0 = *(const float4*)&As[k][ty * 8];
            float4 a1 = *(const float4*)&As[k][ty * 8 + 4];
            float4 b0 = *(const float4*)&Ws[k][tx * 8];
            float4 b1 = *(const float4*)&Ws[k][tx * 8 + 4];
            float a[8] = {a0.x, a0.y, a0.z, a0.w, a1.x, a1.y, a1.z, a1.w};
            float b[8] = {b0.x, b0.y, b0.z, b0.w, b1.x, b1.y, b1.z, b1.w};
#pragma unroll
            for (int i = 0; i < 8; i++)
#pragma unroll
                for (int j = 0; j < 8; j++) acc[i][j] += a[i] * b[j];
        }
    }

    const bool do_add = flags & 1, do_relu = flags & 2;
#pragma unroll
    for (int i = 0; i < 8; i++) {
        int gr = row0 + ty * 8 + i;
        if (gr >= M) continue;
#pragma unroll
        for (int j = 0; j < 8; j += 4) {
            int gc = col0 + tx * 8 + j;
            float4 v = make_float4(acc[i][j], acc[i][j + 1], acc[i][j + 2], acc[i][j + 3]);
            if (bias) {
                v.x += bias[gc]; v.y += bias[gc + 1];
                v.z += bias[gc + 2]; v.w += bias[gc + 3];
            }
            float4* cp = (float4*)(C + (size_t)gr * N + gc);
            if (do_add) {
                float4 o = *cp;
                v.x += o.x; v.y += o.y; v.z += o.z; v.w += o.w;
            }
            if (do_relu) {
                v.x = fmaxf(v.x, 0.f); v.y = fmaxf(v.y, 0.f);
                v.z = fmaxf(v.z, 0.f); v.w = fmaxf(v.w, 0.f);
            }
            *cp = v;
        }
    }
}

// --------------------------- CSR build -------------------------------------
__global__ void count_kernel(const int* __restrict__ src, const int* __restrict__ dst,
                             int* __restrict__ cnt_s, int* __restrict__ cnt_t, int E)
{
    int e = blockIdx.x * blockDim.x + threadIdx.x;
    if (e < E) {
        atomicAdd(&cnt_s[src[e]], 1);
        atomicAdd(&cnt_t[dst[e]], 1);
    }
}

// per-block (1024-elem) sums
__global__ __launch_bounds__(256) void partial_sum_kernel(
    const int* __restrict__ cnt, int* __restrict__ bsum, int N)
{
    __shared__ int sdata[256];
    const int t = threadIdx.x;
    const int base = blockIdx.x * 1024;
    int s = 0;
    for (int i = t; i < 1024; i += 256) {
        int idx = base + i;
        s += (idx < N) ? cnt[idx] : 0;
    }
    sdata[t] = s; __syncthreads();
    for (int off = 128; off > 0; off >>= 1) {
        if (t < off) sdata[t] += sdata[t + off];
        __syncthreads();
    }
    if (t == 0) bsum[blockIdx.x] = sdata[0];
}

// exclusive scan of block sums (nb <= 128, single thread is fine)
__global__ void scan_bsum_kernel(int* __restrict__ bsum, int nb)
{
    if (blockIdx.x == 0 && threadIdx.x == 0) {
        int run = 0;
        for (int i = 0; i < nb; i++) { int v = bsum[i]; bsum[i] = run; run += v; }
    }
}

// per-block exclusive scan + block offset -> rowptr[N+1]
__global__ __launch_bounds__(256) void scan_block_kernel(
    const int* __restrict__ cnt, const int* __restrict__ bsum,
    int* __restrict__ rowptr, int N)
{
    __shared__ int sc[256];
    const int t = threadIdx.x;
    const int base = blockIdx.x * 1024 + t * 4;
    int v[4]; int s = 0;
#pragma unroll
    for (int j = 0; j < 4; j++) {
        int idx = base + j;
        v[j] = (idx < N) ? cnt[idx] : 0;
        s += v[j];
    }
    sc[t] = s; __syncthreads();
    for (int off = 1; off < 256; off <<= 1) {
        int add = (t >= off) ? sc[t - off] : 0;
        __syncthreads();
        sc[t] += add;
        __syncthreads();
    }
    int excl = sc[t] - s + bsum[blockIdx.x];
#pragma unroll
    for (int j = 0; j < 4; j++) {
        int idx = base + j;
        if (idx < N) rowptr[idx] = excl;
        if (idx == N - 1) rowptr[N] = excl + v[j];
        excl += v[j];
    }
}

__global__ void copy_int_kernel(const int* __restrict__ a, int* __restrict__ b, int n)
{
    int i = blockIdx.x * blockDim.x + threadIdx.x;
    if (i < n) b[i] = a[i];
}

// fill neighbor lists via atomic cursors (cursor pre-initialized to rowptr)
__global__ void fill_kernel(const int* __restrict__ src, const int* __restrict__ dst,
                            int* __restrict__ cur_s, int* __restrict__ cur_t,
                            int* __restrict__ col_s, int* __restrict__ col_t, int E)
{
    int e = blockIdx.x * blockDim.x + threadIdx.x;
    if (e < E) {
        int s = src[e], d = dst[e];
        int pt = atomicAdd(&cur_t[d], 1);
        col_t[pt] = s;
        int ps = atomicAdd(&cur_s[s], 1);
        col_s[ps] = d;
    }
}

// ----------------------- gather mean aggregation ---------------------------
// out[n][:] = mean_{i in rowptr[n]..rowptr[n+1]} X[col[i]][:]
// D/4 threads per node; 256-thread blocks.
__global__ __launch_bounds__(256) void gather_mean_kernel(
    const float* __restrict__ X, const int* __restrict__ rowptr,
    const int* __restrict__ col, float* __restrict__ out, int N, int D)
{
    const int tpn = D >> 2;                    // threads per node (64 or 32)
    const int npb = 256 / tpn;                 // nodes per block
    const int node = blockIdx.x * npb + threadIdx.x / tpn;
    const int c = (threadIdx.x % tpn) * 4;
    if (node >= N) return;
    const int beg = rowptr[node], end = rowptr[node + 1];
    float4 acc0 = make_float4(0.f, 0.f, 0.f, 0.f);
    float4 acc1 = make_float4(0.f, 0.f, 0.f, 0.f);
    int i = beg;
    for (; i + 1 < end; i += 2) {
        int n0 = col[i], n1 = col[i + 1];
        float4 v0 = *(const float4*)&X[(size_t)n0 * D + c];
        float4 v1 = *(const float4*)&X[(size_t)n1 * D + c];
        acc0.x += v0.x; acc0.y += v0.y; acc0.z += v0.z; acc0.w += v0.w;
        acc1.x += v1.x; acc1.y += v1.y; acc1.z += v1.z; acc1.w += v1.w;
    }
    if (i < end) {
        float4 v0 = *(const float4*)&X[(size_t)col[i] * D + c];
        acc0.x += v0.x; acc0.y += v0.y; acc0.z += v0.z; acc0.w += v0.w;
    }
    float inv = 1.f / fmaxf((float)(end - beg), 1.f);
    float4 r;
    r.x = (acc0.x + acc1.x) * inv; r.y = (acc0.y + acc1.y) * inv;
    r.z = (acc0.z + acc1.z) * inv; r.w = (acc0.w + acc1.w) * inv;
    *(float4*)&out[(size_t)node * D + c] = r;
}

// ----------------------------- decoder -------------------------------------
// out[e] = Wd2 . relu(Wd1 @ concat(z_s[ls[e]], z_t[ld[e]]) + bd1) + bd2
// Register-blocked GEMM: 64 edges x 256 hidden per block, K=512, BK=32.
// Thread (ty,tx): ty=tid>>5 -> 8 edges (ty*8+i); tx=tid&31 -> 8 cols (64j+2tx+u).
// LDS layouts chosen for bank behavior:
//   Zs[32][68]: rows 272B (16B-aligned) -> b128 broadcast reads; <=4-way writes.
//   Ws[32][258]: bank=(2k+col)%32 -> conflict-free float2 reads; <=2-way writes.
constexpr int DBM = 64, DBK = 32;

__global__ __launch_bounds__(256) void decoder_kernel(
    const float* __restrict__ z_s, const float* __restrict__ z_t,
    const int* __restrict__ ls, const int* __restrict__ ld,
    const float* __restrict__ Wd1, const float* __restrict__ bd1,
    const float* __restrict__ Wd2, const float* __restrict__ bd2,
    float* __restrict__ out, int EL)
{
    __shared__ float Zs[DBK][68];
    __shared__ float Ws[DBK][258];
    __shared__ int es[DBM], et[DBM];

    const int tid = threadIdx.x;
    const int e0 = blockIdx.x * DBM;
    if (tid < DBM) {
        int ge = min(e0 + tid, EL - 1);
        es[tid] = ls[ge];
        et[tid] = ld[ge];
    }

    const int ty = tid >> 5;   // 0..7
    const int tx = tid & 31;   // 0..31

    float acc[8][8];
#pragma unroll
    for (int i = 0; i < 8; i++)
#pragma unroll
        for (int j = 0; j < 8; j++) acc[i][j] = 0.f;

    for (int k0 = 0; k0 < 512; k0 += DBK) {
        const float* __restrict__ src = (k0 < 256) ? z_s : z_t;
        const int* eidx = (k0 < 256) ? es : et;
        const int kb = k0 & 255;
        __syncthreads();   // protects prev-iter reads AND es/et staging (iter 0)
        // stage Z: 64 edges x 32 k = 512 float4 -> 2 per thread
#pragma unroll
        for (int t = 0; t < 2; t++) {
            int idx = t * 256 + tid;
            int r = idx >> 3, kc = (idx & 7) * 4;
            float4 v = *(const float4*)&src[(size_t)eidx[r] * 256 + kb + kc];
            Zs[kc + 0][r] = v.x; Zs[kc + 1][r] = v.y;
            Zs[kc + 2][r] = v.z; Zs[kc + 3][r] = v.w;
        }
        // stage W: 256 cols x 32 k = 2048 float4 -> 8 per thread
#pragma unroll
        for (int t = 0; t < 8; t++) {
            int idx = t * 256 + tid;
            int cc = idx >> 3, kc = (idx & 7) * 4;
            float4 v = *(const float4*)&Wd1[(size_t)cc * 512 + k0 + kc];
            Ws[kc + 0][cc] = v.x; Ws[kc + 1][cc] = v.y;
            Ws[kc + 2][cc] = v.z; Ws[kc + 3][cc] = v.w;
        }
        __syncthreads();
#pragma unroll
        for (int k = 0; k < DBK; k++) {
            float4 a0 = *(const float4*)&Zs[k][ty * 8];
            float4 a1 = *(const float4*)&Zs[k][ty * 8 + 4];
            float av[8] = {a0.x, a0.y, a0.z, a0.w, a1.x, a1.y, a1.z, a1.w};
            float bv[8];
#pragma unroll
            for (int j = 0; j < 4; j++) {
                float2 b = *(const float2*)&Ws[k][64 * j + 2 * tx];
                bv[2 * j] = b.x; bv[2 * j + 1] = b.y;
            }
#pragma unroll
            for (int i = 0; i < 8; i++)
#pragma unroll
                for (int j = 0; j < 8; j++) acc[i][j] += av[i] * bv[j];
        }
    }

    // epilogue: bias + relu + dot(Wd2) per thread, shfl-reduce over tx
    float bb[8], w2[8];
#pragma unroll
    for (int j = 0; j < 4; j++) {
        int c = 64 * j + 2 * tx;
        float2 b = *(const float2*)&bd1[c];
        float2 w = *(const float2*)&Wd2[c];
        bb[2 * j] = b.x; bb[2 * j + 1] = b.y;
        w2[2 * j] = w.x; w2[2 * j + 1] = w.y;
    }
    const float bias2 = bd2[0];
#pragma unroll
    for (int i = 0; i < 8; i++) {
        float s = 0.f;
#pragma unroll
        for (int j = 0; j < 8; j++)
            s += fmaxf(acc[i][j] + bb[j], 0.f) * w2[j];
#pragma unroll
        for (int m = 16; m >= 1; m >>= 1)
            s += __shfl_xor(s, m, 64);   // masks <32: reduces within 32-lane halves
        if (tx == 0) {
            int ge = e0 + ty * 8 + i;
            if (ge < EL) out[ge] = s + bias2;
        }
    }
}

// ---------------------------------------------------------------------------
extern "C" void kernel_launch(void* const* d_in, const int* in_sizes, int n_in,
                              void* d_out, int out_size, void* d_ws, size_t ws_size,
                              hipStream_t stream)
{
    const float* x_sotu  = (const float*)d_in[0];
    const float* x_taxon = (const float*)d_in[1];
    const int* edge_src  = (const int*)d_in[2];
    const int* edge_dst  = (const int*)d_in[3];
    const int* label_src = (const int*)d_in[4];
    const int* label_dst = (const int*)d_in[5];
    const float* Wl1_st = (const float*)d_in[6];
    const float* bl1_st = (const float*)d_in[7];
    const float* Wr1_st = (const float*)d_in[8];
    const float* Wl1_ts = (const float*)d_in[9];
    const float* bl1_ts = (const float*)d_in[10];
    const float* Wr1_ts = (const float*)d_in[11];
    const float* Wl2_st = (const float*)d_in[12];
    const float* bl2_st = (const float*)d_in[13];
    const float* Wr2_st = (const float*)d_in[14];
    const float* Wl2_ts = (const float*)d_in[15];
    const float* bl2_ts = (const float*)d_in[16];
    const float* Wr2_ts = (const float*)d_in[17];
    const float* Wlin_s = (const float*)d_in[18];
    const float* blin_s = (const float*)d_in[19];
    const float* Wlin_t = (const float*)d_in[20];
    const float* blin_t = (const float*)d_in[21];
    const float* Wd1 = (const float*)d_in[22];
    const float* bd1 = (const float*)d_in[23];
    const float* Wd2 = (const float*)d_in[24];
    const float* bd2 = (const float*)d_in[25];

    // -------- workspace layout --------
    int* wi = (int*)d_ws;
    size_t io = 0;
    int* cnt_s   = wi + io; io += NS;
    int* cnt_t   = wi + io; io += NT;
    int* rowptr_s = wi + io; io += NS + 4;
    int* rowptr_t = wi + io; io += NT + 4;
    int* cur_s   = wi + io; io += NS;
    int* cur_t   = wi + io; io += NT;
    int* col_s   = wi + io; io += E_EDGES;
    int* col_t   = wi + io; io += E_EDGES;
    int* bsum_s  = wi + io; io += 128;
    int* bsum_t  = wi + io; io += 128;
    io = (io + 3) & ~(size_t)3;

    float* ws = (float*)(wi + io);
    size_t o = 0;
    float* m_s  = ws + o; o += (size_t)NS * H;
    float* m_t  = ws + o; o += (size_t)NT * H;
    float* h1_s = ws + o; o += (size_t)NS * H;
    float* h1_t = ws + o; o += (size_t)NT * H;
    float* h2_s = ws + o; o += (size_t)NS * H;
    float* h2_t = ws + o; o += (size_t)NT * H;
    float* z_s = m_s;   // reuse (messages dead by then)
    float* z_t = m_t;

    const dim3 blk(256);
    auto grd = [](int M) { return dim3((M + BM - 1) / BM, H / BN); };
    const int nbS = (NS + 1023) / 1024;   // 98
    const int nbT = (NT + 1023) / 1024;   // 20

    // ---- CSR build (both directions) ----
    hipMemsetAsync(cnt_s, 0, (size_t)(NS + NT) * sizeof(int), stream);
    count_kernel<<<(E_EDGES + 255) / 256, blk, 0, stream>>>(edge_src, edge_dst,
                                                            cnt_s, cnt_t, E_EDGES);
    partial_sum_kernel<<<nbS, blk, 0, stream>>>(cnt_s, bsum_s, NS);
    partial_sum_kernel<<<nbT, blk, 0, stream>>>(cnt_t, bsum_t, NT);
    scan_bsum_kernel<<<1, 64, 0, stream>>>(bsum_s, nbS);
    scan_bsum_kernel<<<1, 64, 0, stream>>>(bsum_t, nbT);
    scan_block_kernel<<<nbS, blk, 0, stream>>>(cnt_s, bsum_s, rowptr_s, NS);
    scan_block_kernel<<<nbT, blk, 0, stream>>>(cnt_t, bsum_t, rowptr_t, NT);
    copy_int_kernel<<<(NS + 255) / 256, blk, 0, stream>>>(rowptr_s, cur_s, NS);
    copy_int_kernel<<<(NT + 255) / 256, blk, 0, stream>>>(rowptr_t, cur_t, NT);
    fill_kernel<<<(E_EDGES + 255) / 256, blk, 0, stream>>>(
        edge_src, edge_dst, cur_s, cur_t, col_s, col_t, E_EDGES);

    // ---- layer 1 aggregation (gather, mean fused) ----
    gather_mean_kernel<<<(NT * 64 + 255) / 256, blk, 0, stream>>>(
        x_sotu, rowptr_t, col_t, m_t, NT, DS);
    gather_mean_kernel<<<(NS * 32 + 255) / 256, blk, 0, stream>>>(
        x_taxon, rowptr_s, col_s, m_s, NS, DT);

    // ---- layer 1 GEMMs ----
    gemm_kernel<<<grd(NT), blk, 0, stream>>>(m_t, Wl1_st, bl1_st, h1_t, NT, H, 256, 0);
    gemm_kernel<<<grd(NT), blk, 0, stream>>>(x_taxon, Wr1_st, nullptr, h1_t, NT, H, 128, 3);
    gemm_kernel<<<grd(NS), blk, 0, stream>>>(m_s, Wl1_ts, bl1_ts, h1_s, NS, H, 128, 0);
    gemm_kernel<<<grd(NS), blk, 0, stream>>>(x_sotu, Wr1_ts, nullptr, h1_s, NS, H, 256, 3);

    // ---- layer 2 aggregation ----
    gather_mean_kernel<<<(NT * 64 + 255) / 256, blk, 0, stream>>>(
        h1_s, rowptr_t, col_t, m_t, NT, H);
    gather_mean_kernel<<<(NS * 64 + 255) / 256, blk, 0, stream>>>(
        h1_t, rowptr_s, col_s, m_s, NS, H);

    // ---- layer 2 GEMMs ----
    gemm_kernel<<<grd(NT), blk, 0, stream>>>(m_t, Wl2_st, bl2_st, h2_t, NT, H, 256, 0);
    gemm_kernel<<<grd(NT), blk, 0, stream>>>(h1_t, Wr2_st, nullptr, h2_t, NT, H, 256, 3);
    gemm_kernel<<<grd(NS), blk, 0, stream>>>(m_s, Wl2_ts, bl2_ts, h2_s, NS, H, 256, 0);
    gemm_kernel<<<grd(NS), blk, 0, stream>>>(h1_s, Wr2_ts, nullptr, h2_s, NS, H, 256, 3);

    // ---- per-type projection ----
    gemm_kernel<<<grd(NS), blk, 0, stream>>>(h2_s, Wlin_s, blin_s, z_s, NS, H, 256, 0);
    gemm_kernel<<<grd(NT), blk, 0, stream>>>(h2_t, Wlin_t, blin_t, z_t, NT, H, 256, 0);

    // ---- fused edge decoder ----
    decoder_kernel<<<(EL_EDGES + DBM - 1) / DBM, blk, 0, stream>>>(
        z_s, z_t, label_src, label_dst, Wd1, bd1, Wd2, bd2,
        (float*)d_out, EL_EDGES);
}

// Round 4
// 2501.837 us; speedup vs baseline: 5.0380x; 1.0186x over previous
//
#include <hip/hip_runtime.h>

// ---------------------------------------------------------------------------
// Hetero GraphSAGE (2 layers) + per-type linear + edge MLP decoder, fp32.
// R1: CSR-gather aggregation (killed 3.28GB/dispatch atomic write-through).
// R2: decoder as register-blocked GEMM (64x256, BK=32) — 1.69ms -> 0.70ms.
// R3: decoder BK=16 (LDS 42.5->21KB, occupancy 21%->~55%) to hide barrier
//     drains; fused dual-GEMM (relu(A1@W1^T + A2@W2^T + b)) removes the
//     C read-modify-write round-trip and 4 launches.
// ---------------------------------------------------------------------------

constexpr int NS = 100000, NT = 20000;
constexpr int E_EDGES = 800000, EL_EDGES = 200000;
constexpr int DS = 256, DT = 128, H = 256;

// ------------------------------ GEMM ---------------------------------------
constexpr int BM = 128, BN = 128, BK = 8;

// C[M,N] = A[M,K] @ W[N,K]^T + bias   (single pair, used for projections)
__global__ __launch_bounds__(256) void gemm_kernel(
    const float* __restrict__ A, const float* __restrict__ W,
    const float* __restrict__ bias, float* __restrict__ C,
    int M, int N, int K)
{
    __shared__ float As[BK][BM];
    __shared__ float Ws[BK][BN];
    const int tid = threadIdx.x;
    const int row0 = blockIdx.x * BM, col0 = blockIdx.y * BN;
    const int tx = tid & 15, ty = tid >> 4;
    const int lr = tid >> 1;
    const int lk = (tid & 1) * 4;

    float acc[8][8];
#pragma unroll
    for (int i = 0; i < 8; i++)
#pragma unroll
        for (int j = 0; j < 8; j++) acc[i][j] = 0.f;

    const bool arow_ok = (row0 + lr) < M;
    const float* Ap = A + (size_t)(row0 + lr) * K + lk;
    const float* Wp = W + (size_t)(col0 + lr) * K + lk;

    for (int k0 = 0; k0 < K; k0 += BK) {
        float4 av = make_float4(0.f, 0.f, 0.f, 0.f);
        if (arow_ok) av = *(const float4*)(Ap + k0);
        float4 wv = *(const float4*)(Wp + k0);
        __syncthreads();
        As[lk + 0][lr] = av.x; As[lk + 1][lr] = av.y;
        As[lk + 2][lr] = av.z; As[lk + 3][lr] = av.w;
        Ws[lk + 0][lr] = wv.x; Ws[lk + 1][lr] = wv.y;
        Ws[lk + 2][lr] = wv.z; Ws[lk + 3][lr] = wv.w;
        __syncthreads();
#pragma unroll
        for (int k = 0; k < BK; k++) {
            float4 a0 = *(const float4*)&As[k][ty * 8];
            float4 a1 = *(const float4*)&As[k][ty * 8 + 4];
            float4 b0 = *(const float4*)&Ws[k][tx * 8];
            float4 b1 = *(const float4*)&Ws[k][tx * 8 + 4];
            float a[8] = {a0.x, a0.y, a0.z, a0.w, a1.x, a1.y, a1.z, a1.w};
            float b[8] = {b0.x, b0.y, b0.z, b0.w, b1.x, b1.y, b1.z, b1.w};
#pragma unroll
            for (int i = 0; i < 8; i++)
#pragma unroll
                for (int j = 0; j < 8; j++) acc[i][j] += a[i] * b[j];
        }
    }

#pragma unroll
    for (int i = 0; i < 8; i++) {
        int gr = row0 + ty * 8 + i;
        if (gr >= M) continue;
#pragma unroll
        for (int j = 0; j < 8; j += 4) {
            int gc = col0 + tx * 8 + j;
            float4 v = make_float4(acc[i][j], acc[i][j + 1], acc[i][j + 2], acc[i][j + 3]);
            v.x += bias[gc]; v.y += bias[gc + 1];
            v.z += bias[gc + 2]; v.w += bias[gc + 3];
            *(float4*)(C + (size_t)gr * N + gc) = v;
        }
    }
}

// C[M,N] = relu(A1@W1^T + A2@W2^T + bias) — fused SAGE layer (lin_l + lin_r)
__global__ __launch_bounds__(256) void gemm2_kernel(
    const float* __restrict__ A1, const float* __restrict__ W1, int K1,
    const float* __restrict__ A2, const float* __restrict__ W2, int K2,
    const float* __restrict__ bias, float* __restrict__ C,
    int M, int N)
{
    __shared__ float As[BK][BM];
    __shared__ float Ws[BK][BN];
    const int tid = threadIdx.x;
    const int row0 = blockIdx.x * BM, col0 = blockIdx.y * BN;
    const int tx = tid & 15, ty = tid >> 4;
    const int lr = tid >> 1;
    const int lk = (tid & 1) * 4;

    float acc[8][8];
#pragma unroll
    for (int i = 0; i < 8; i++)
#pragma unroll
        for (int j = 0; j < 8; j++) acc[i][j] = 0.f;

    const bool arow_ok = (row0 + lr) < M;

#pragma unroll 1
    for (int pass = 0; pass < 2; pass++) {
        const float* A = pass ? A2 : A1;
        const float* W = pass ? W2 : W1;
        const int K = pass ? K2 : K1;
        const float* Ap = A + (size_t)(row0 + lr) * K + lk;
        const float* Wp = W + (size_t)(col0 + lr) * K + lk;
        for (int k0 = 0; k0 < K; k0 += BK) {
            float4 av = make_float4(0.f, 0.f, 0.f, 0.f);
            if (arow_ok) av = *(const float4*)(Ap + k0);
            float4 wv = *(const float4*)(Wp + k0);
            __syncthreads();
            As[lk + 0][lr] = av.x; As[lk + 1][lr] = av.y;
            As[lk + 2][lr] = av.z; As[lk + 3][lr] = av.w;
            Ws[lk + 0][lr] = wv.x; Ws[lk + 1][lr] = wv.y;
            Ws[lk + 2][lr] = wv.z; Ws[lk + 3][lr] = wv.w;
            __syncthreads();
#pragma unroll
            for (int k = 0; k < BK; k++) {
                float4 a0 = *(const float4*)&As[k][ty * 8];
                float4 a1 = *(const float4*)&As[k][ty * 8 + 4];
                float4 b0 = *(const float4*)&Ws[k][tx * 8];
                float4 b1 = *(const float4*)&Ws[k][tx * 8 + 4];
                float a[8] = {a0.x, a0.y, a0.z, a0.w, a1.x, a1.y, a1.z, a1.w};
                float b[8] = {b0.x, b0.y, b0.z, b0.w, b1.x, b1.y, b1.z, b1.w};
#pragma unroll
                for (int i = 0; i < 8; i++)
#pragma unroll
                    for (int j = 0; j < 8; j++) acc[i][j] += a[i] * b[j];
            }
        }
    }

#pragma unroll
    for (int i = 0; i < 8; i++) {
        int gr = row0 + ty * 8 + i;
        if (gr >= M) continue;
#pragma unroll
        for (int j = 0; j < 8; j += 4) {
            int gc = col0 + tx * 8 + j;
            float4 v = make_float4(acc[i][j], acc[i][j + 1], acc[i][j + 2], acc[i][j + 3]);
            v.x = fmaxf(v.x + bias[gc], 0.f);
            v.y = fmaxf(v.y + bias[gc + 1], 0.f);
            v.z = fmaxf(v.z + bias[gc + 2], 0.f);
            v.w = fmaxf(v.w + bias[gc + 3], 0.f);
            *(float4*)(C + (size_t)gr * N + gc) = v;
        }
    }
}

// --------------------------- CSR build -------------------------------------
__global__ void count_kernel(const int* __restrict__ src, const int* __restrict__ dst,
                             int* __restrict__ cnt_s, int* __restrict__ cnt_t, int E)
{
    int e = blockIdx.x * blockDim.x + threadIdx.x;
    if (e < E) {
        atomicAdd(&cnt_s[src[e]], 1);
        atomicAdd(&cnt_t[dst[e]], 1);
    }
}

__global__ __launch_bounds__(256) void partial_sum_kernel(
    const int* __restrict__ cnt, int* __restrict__ bsum, int N)
{
    __shared__ int sdata[256];
    const int t = threadIdx.x;
    const int base = blockIdx.x * 1024;
    int s = 0;
    for (int i = t; i < 1024; i += 256) {
        int idx = base + i;
        s += (idx < N) ? cnt[idx] : 0;
    }
    sdata[t] = s; __syncthreads();
    for (int off = 128; off > 0; off >>= 1) {
        if (t < off) sdata[t] += sdata[t + off];
        __syncthreads();
    }
    if (t == 0) bsum[blockIdx.x] = sdata[0];
}

__global__ void scan_bsum_kernel(int* __restrict__ bsum, int nb)
{
    if (blockIdx.x == 0 && threadIdx.x == 0) {
        int run = 0;
        for (int i = 0; i < nb; i++) { int v = bsum[i]; bsum[i] = run; run += v; }
    }
}

__global__ __launch_bounds__(256) void scan_block_kernel(
    const int* __restrict__ cnt, const int* __restrict__ bsum,
    int* __restrict__ rowptr, int N)
{
    __shared__ int sc[256];
    const int t = threadIdx.x;
    const int base = blockIdx.x * 1024 + t * 4;
    int v[4]; int s = 0;
#pragma unroll
    for (int j = 0; j < 4; j++) {
        int idx = base + j;
        v[j] = (idx < N) ? cnt[idx] : 0;
        s += v[j];
    }
    sc[t] = s; __syncthreads();
    for (int off = 1; off < 256; off <<= 1) {
        int add = (t >= off) ? sc[t - off] : 0;
        __syncthreads();
        sc[t] += add;
        __syncthreads();
    }
    int excl = sc[t] - s + bsum[blockIdx.x];
#pragma unroll
    for (int j = 0; j < 4; j++) {
        int idx = base + j;
        if (idx < N) rowptr[idx] = excl;
        if (idx == N - 1) rowptr[N] = excl + v[j];
        excl += v[j];
    }
}

__global__ void copy_int_kernel(const int* __restrict__ a, int* __restrict__ b, int n)
{
    int i = blockIdx.x * blockDim.x + threadIdx.x;
    if (i < n) b[i] = a[i];
}

__global__ void fill_kernel(const int* __restrict__ src, const int* __restrict__ dst,
                            int* __restrict__ cur_s, int* __restrict__ cur_t,
                            int* __restrict__ col_s, int* __restrict__ col_t, int E)
{
    int e = blockIdx.x * blockDim.x + threadIdx.x;
    if (e < E) {
        int s = src[e], d = dst[e];
        int pt = atomicAdd(&cur_t[d], 1);
        col_t[pt] = s;
        int ps = atomicAdd(&cur_s[s], 1);
        col_s[ps] = d;
    }
}

// ----------------------- gather mean aggregation ---------------------------
__global__ __launch_bounds__(256) void gather_mean_kernel(
    const float* __restrict__ X, const int* __restrict__ rowptr,
    const int* __restrict__ col, float* __restrict__ out, int N, int D)
{
    const int tpn = D >> 2;
    const int npb = 256 / tpn;
    const int node = blockIdx.x * npb + threadIdx.x / tpn;
    const int c = (threadIdx.x % tpn) * 4;
    if (node >= N) return;
    const int beg = rowptr[node], end = rowptr[node + 1];
    float4 acc0 = make_float4(0.f, 0.f, 0.f, 0.f);
    float4 acc1 = make_float4(0.f, 0.f, 0.f, 0.f);
    int i = beg;
    for (; i + 1 < end; i += 2) {
        int n0 = col[i], n1 = col[i + 1];
        float4 v0 = *(const float4*)&X[(size_t)n0 * D + c];
        float4 v1 = *(const float4*)&X[(size_t)n1 * D + c];
        acc0.x += v0.x; acc0.y += v0.y; acc0.z += v0.z; acc0.w += v0.w;
        acc1.x += v1.x; acc1.y += v1.y; acc1.z += v1.z; acc1.w += v1.w;
    }
    if (i < end) {
        float4 v0 = *(const float4*)&X[(size_t)col[i] * D + c];
        acc0.x += v0.x; acc0.y += v0.y; acc0.z += v0.z; acc0.w += v0.w;
    }
    float inv = 1.f / fmaxf((float)(end - beg), 1.f);
    float4 r;
    r.x = (acc0.x + acc1.x) * inv; r.y = (acc0.y + acc1.y) * inv;
    r.z = (acc0.z + acc1.z) * inv; r.w = (acc0.w + acc1.w) * inv;
    *(float4*)&out[(size_t)node * D + c] = r;
}

// ----------------------------- decoder -------------------------------------
// out[e] = Wd2 . relu(Wd1 @ concat(z_s[ls[e]], z_t[ld[e]]) + bd1) + bd2
// 64 edges x 256 hidden per block, K=512, BK=16 (LDS ~21KB -> ~5 blocks/CU).
constexpr int DBM = 64, DBK = 16;

__global__ __launch_bounds__(256) void decoder_kernel(
    const float* __restrict__ z_s, const float* __restrict__ z_t,
    const int* __restrict__ ls, const int* __restrict__ ld,
    const float* __restrict__ Wd1, const float* __restrict__ bd1,
    const float* __restrict__ Wd2, const float* __restrict__ bd2,
    float* __restrict__ out, int EL)
{
    __shared__ float Zs[DBK][68];
    __shared__ float Ws[DBK][258];
    __shared__ int es[DBM], et[DBM];

    const int tid = threadIdx.x;
    const int e0 = blockIdx.x * DBM;
    if (tid < DBM) {
        int ge = min(e0 + tid, EL - 1);
        es[tid] = ls[ge];
        et[tid] = ld[ge];
    }

    const int ty = tid >> 5;   // 0..7 -> 8 edges each
    const int tx = tid & 31;   // 0..31 -> 8 cols (64j + 2tx + u)

    float acc[8][8];
#pragma unroll
    for (int i = 0; i < 8; i++)
#pragma unroll
        for (int j = 0; j < 8; j++) acc[i][j] = 0.f;

    for (int k0 = 0; k0 < 512; k0 += DBK) {
        const float* __restrict__ src = (k0 < 256) ? z_s : z_t;
        const int* eidx = (k0 < 256) ? es : et;
        const int kb = k0 & 255;
        __syncthreads();   // protects prev-iter reads AND es/et staging (iter 0)
        // stage Z: 64 edges x 16 k = 256 float4 -> 1 per thread
        {
            int r = tid >> 2, kc = (tid & 3) * 4;
            float4 v = *(const float4*)&src[(size_t)eidx[r] * 256 + kb + kc];
            Zs[kc + 0][r] = v.x; Zs[kc + 1][r] = v.y;
            Zs[kc + 2][r] = v.z; Zs[kc + 3][r] = v.w;
        }
        // stage W: 256 cols x 16 k = 1024 float4 -> 4 per thread
#pragma unroll
        for (int t = 0; t < 4; t++) {
            int idx = t * 256 + tid;
            int cc = idx >> 2, kc = (idx & 3) * 4;
            float4 v = *(const float4*)&Wd1[(size_t)cc * 512 + k0 + kc];
            Ws[kc + 0][cc] = v.x; Ws[kc + 1][cc] = v.y;
            Ws[kc + 2][cc] = v.z; Ws[kc + 3][cc] = v.w;
        }
        __syncthreads();
#pragma unroll
        for (int k = 0; k < DBK; k++) {
            float4 a0 = *(const float4*)&Zs[k][ty * 8];
            float4 a1 = *(const float4*)&Zs[k][ty * 8 + 4];
            float av[8] = {a0.x, a0.y, a0.z, a0.w, a1.x, a1.y, a1.z, a1.w};
            float bv[8];
#pragma unroll
            for (int j = 0; j < 4; j++) {
                float2 b = *(const float2*)&Ws[k][64 * j + 2 * tx];
                bv[2 * j] = b.x; bv[2 * j + 1] = b.y;
            }
#pragma unroll
            for (int i = 0; i < 8; i++)
#pragma unroll
                for (int j = 0; j < 8; j++) acc[i][j] += av[i] * bv[j];
        }
    }

    // epilogue: bias + relu + dot(Wd2), shfl-reduce over the 32 tx lanes
    float bb[8], w2[8];
#pragma unroll
    for (int j = 0; j < 4; j++) {
        int c = 64 * j + 2 * tx;
        float2 b = *(const float2*)&bd1[c];
        float2 w = *(const float2*)&Wd2[c];
        bb[2 * j] = b.x; bb[2 * j + 1] = b.y;
        w2[2 * j] = w.x; w2[2 * j + 1] = w.y;
    }
    const float bias2 = bd2[0];
#pragma unroll
    for (int i = 0; i < 8; i++) {
        float s = 0.f;
#pragma unroll
        for (int j = 0; j < 8; j++)
            s += fmaxf(acc[i][j] + bb[j], 0.f) * w2[j];
#pragma unroll
        for (int m = 16; m >= 1; m >>= 1)
            s += __shfl_xor(s, m, 64);
        if (tx == 0) {
            int ge = e0 + ty * 8 + i;
            if (ge < EL) out[ge] = s + bias2;
        }
    }
}

// ---------------------------------------------------------------------------
extern "C" void kernel_launch(void* const* d_in, const int* in_sizes, int n_in,
                              void* d_out, int out_size, void* d_ws, size_t ws_size,
                              hipStream_t stream)
{
    const float* x_sotu  = (const float*)d_in[0];
    const float* x_taxon = (const float*)d_in[1];
    const int* edge_src  = (const int*)d_in[2];
    const int* edge_dst  = (const int*)d_in[3];
    const int* label_src = (const int*)d_in[4];
    const int* label_dst = (const int*)d_in[5];
    const float* Wl1_st = (const float*)d_in[6];
    const float* bl1_st = (const float*)d_in[7];
    const float* Wr1_st = (const float*)d_in[8];
    const float* Wl1_ts = (const float*)d_in[9];
    const float* bl1_ts = (const float*)d_in[10];
    const float* Wr1_ts = (const float*)d_in[11];
    const float* Wl2_st = (const float*)d_in[12];
    const float* bl2_st = (const float*)d_in[13];
    const float* Wr2_st = (const float*)d_in[14];
    const float* Wl2_ts = (const float*)d_in[15];
    const float* bl2_ts = (const float*)d_in[16];
    const float* Wr2_ts = (const float*)d_in[17];
    const float* Wlin_s = (const float*)d_in[18];
    const float* blin_s = (const float*)d_in[19];
    const float* Wlin_t = (const float*)d_in[20];
    const float* blin_t = (const float*)d_in[21];
    const float* Wd1 = (const float*)d_in[22];
    const float* bd1 = (const float*)d_in[23];
    const float* Wd2 = (const float*)d_in[24];
    const float* bd2 = (const float*)d_in[25];

    // -------- workspace layout --------
    int* wi = (int*)d_ws;
    size_t io = 0;
    int* cnt_s   = wi + io; io += NS;
    int* cnt_t   = wi + io; io += NT;
    int* rowptr_s = wi + io; io += NS + 4;
    int* rowptr_t = wi + io; io += NT + 4;
    int* cur_s   = wi + io; io += NS;
    int* cur_t   = wi + io; io += NT;
    int* col_s   = wi + io; io += E_EDGES;
    int* col_t   = wi + io; io += E_EDGES;
    int* bsum_s  = wi + io; io += 128;
    int* bsum_t  = wi + io; io += 128;
    io = (io + 3) & ~(size_t)3;

    float* ws = (float*)(wi + io);
    size_t o = 0;
    float* m_s  = ws + o; o += (size_t)NS * H;
    float* m_t  = ws + o; o += (size_t)NT * H;
    float* h1_s = ws + o; o += (size_t)NS * H;
    float* h1_t = ws + o; o += (size_t)NT * H;
    float* h2_s = ws + o; o += (size_t)NS * H;
    float* h2_t = ws + o; o += (size_t)NT * H;
    float* z_s = m_s;   // reuse (messages dead by then)
    float* z_t = m_t;

    const dim3 blk(256);
    auto grd = [](int M) { return dim3((M + BM - 1) / BM, H / BN); };
    const int nbS = (NS + 1023) / 1024;
    const int nbT = (NT + 1023) / 1024;

    // ---- CSR build (both directions) ----
    hipMemsetAsync(cnt_s, 0, (size_t)(NS + NT) * sizeof(int), stream);
    count_kernel<<<(E_EDGES + 255) / 256, blk, 0, stream>>>(edge_src, edge_dst,
                                                            cnt_s, cnt_t, E_EDGES);
    partial_sum_kernel<<<nbS, blk, 0, stream>>>(cnt_s, bsum_s, NS);
    partial_sum_kernel<<<nbT, blk, 0, stream>>>(cnt_t, bsum_t, NT);
    scan_bsum_kernel<<<1, 64, 0, stream>>>(bsum_s, nbS);
    scan_bsum_kernel<<<1, 64, 0, stream>>>(bsum_t, nbT);
    scan_block_kernel<<<nbS, blk, 0, stream>>>(cnt_s, bsum_s, rowptr_s, NS);
    scan_block_kernel<<<nbT, blk, 0, stream>>>(cnt_t, bsum_t, rowptr_t, NT);
    copy_int_kernel<<<(NS + 255) / 256, blk, 0, stream>>>(rowptr_s, cur_s, NS);
    copy_int_kernel<<<(NT + 255) / 256, blk, 0, stream>>>(rowptr_t, cur_t, NT);
    fill_kernel<<<(E_EDGES + 255) / 256, blk, 0, stream>>>(
        edge_src, edge_dst, cur_s, cur_t, col_s, col_t, E_EDGES);

    // ---- layer 1 aggregation (gather, mean fused) ----
    gather_mean_kernel<<<(NT * 64 + 255) / 256, blk, 0, stream>>>(
        x_sotu, rowptr_t, col_t, m_t, NT, DS);
    gather_mean_kernel<<<(NS * 32 + 255) / 256, blk, 0, stream>>>(
        x_taxon, rowptr_s, col_s, m_s, NS, DT);

    // ---- layer 1 fused GEMMs: h1 = relu(m@Wl^T + x@Wr^T + b) ----
    gemm2_kernel<<<grd(NT), blk, 0, stream>>>(m_t, Wl1_st, 256,
                                              x_taxon, Wr1_st, 128,
                                              bl1_st, h1_t, NT, H);
    gemm2_kernel<<<grd(NS), blk, 0, stream>>>(m_s, Wl1_ts, 128,
                                              x_sotu, Wr1_ts, 256,
                                              bl1_ts, h1_s, NS, H);

    // ---- layer 2 aggregation ----
    gather_mean_kernel<<<(NT * 64 + 255) / 256, blk, 0, stream>>>(
        h1_s, rowptr_t, col_t, m_t, NT, H);
    gather_mean_kernel<<<(NS * 64 + 255) / 256, blk, 0, stream>>>(
        h1_t, rowptr_s, col_s, m_s, NS, H);

    // ---- layer 2 fused GEMMs ----
    gemm2_kernel<<<grd(NT), blk, 0, stream>>>(m_t, Wl2_st, 256,
                                              h1_t, Wr2_st, 256,
                                              bl2_st, h2_t, NT, H);
    gemm2_kernel<<<grd(NS), blk, 0, stream>>>(m_s, Wl2_ts, 256,
                                              h1_s, Wr2_ts, 256,
                                              bl2_ts, h2_s, NS, H);

    // ---- per-type projection ----
    gemm_kernel<<<grd(NS), blk, 0, stream>>>(h2_s, Wlin_s, blin_s, z_s, NS, H, 256);
    gemm_kernel<<<grd(NT), blk, 0, stream>>>(h2_t, Wlin_t, blin_t, z_t, NT, H, 256);

    // ---- fused edge decoder ----
    decoder_kernel<<<(EL_EDGES + DBM - 1) / DBM, blk, 0, stream>>>(
        z_s, z_t, label_src, label_dst, Wd1, bd1, Wd2, bd2,
        (float*)d_out, EL_EDGES);
}

// Round 5
// 1873.726 us; speedup vs baseline: 6.7269x; 1.3352x over previous
//
#include <hip/hip_runtime.h>

// ---------------------------------------------------------------------------
// Hetero GraphSAGE (2 layers) + edge MLP decoder, fp32.
// R1: CSR-gather aggregation (killed 3.28GB/dispatch atomic write-through).
// R2/R3: decoder as register-blocked GEMM, BK=16.
// R4: algebraic restructure:
//   (a) decoder: Wd1@concat(zs,zt) = Wd1L@zs + Wd1R@zt; fold Wlin into
//       Wc = Wd1L@Wlin -> per-node U/V GEMMs + tiny per-edge gather-reduce.
//       (z_s/z_t feed only the decoder, so projections fold away exactly.)
//   (b) project-before-aggregate on sotu-destination direction:
//       mean_agg(x)@Wl^T == mean_agg(x@Wl^T); project 20k taxon rows, not
//       100k sotu rows. Layer1 1.31e10->1.3e9, layer2 1.31e10->2.6e9 FLOP.
// Total GEMM FLOP 1.23e11 -> 5.3e10.
// ---------------------------------------------------------------------------

constexpr int NS = 100000, NT = 20000;
constexpr int E_EDGES = 800000, EL_EDGES = 200000;
constexpr int DS = 256, DT = 128, H = 256;

// ------------------------------ GEMM ---------------------------------------
constexpr int BM = 128, BN = 128, BK = 8;

// C[M,N] = A[M,K] @ W[N,K]^T (+ bias if non-null)
__global__ __launch_bounds__(256) void gemm_kernel(
    const float* __restrict__ A, const float* __restrict__ W,
    const float* __restrict__ bias, float* __restrict__ C,
    int M, int N, int K)
{
    __shared__ float As[BK][BM];
    __shared__ float Ws[BK][BN];
    const int tid = threadIdx.x;
    const int row0 = blockIdx.x * BM, col0 = blockIdx.y * BN;
    const int tx = tid & 15, ty = tid >> 4;
    const int lr = tid >> 1;
    const int lk = (tid & 1) * 4;

    float acc[8][8];
#pragma unroll
    for (int i = 0; i < 8; i++)
#pragma unroll
        for (int j = 0; j < 8; j++) acc[i][j] = 0.f;

    const bool arow_ok = (row0 + lr) < M;
    const float* Ap = A + (size_t)(row0 + lr) * K + lk;
    const float* Wp = W + (size_t)(col0 + lr) * K + lk;

    for (int k0 = 0; k0 < K; k0 += BK) {
        float4 av = make_float4(0.f, 0.f, 0.f, 0.f);
        if (arow_ok) av = *(const float4*)(Ap + k0);
        float4 wv = *(const float4*)(Wp + k0);
        __syncthreads();
        As[lk + 0][lr] = av.x; As[lk + 1][lr] = av.y;
        As[lk + 2][lr] = av.z; As[lk + 3][lr] = av.w;
        Ws[lk + 0][lr] = wv.x; Ws[lk + 1][lr] = wv.y;
        Ws[lk + 2][lr] = wv.z; Ws[lk + 3][lr] = wv.w;
        __syncthreads();
#pragma unroll
        for (int k = 0; k < BK; k++) {
            float4 a0 = *(const float4*)&As[k][ty * 8];
            float4 a1 = *(const float4*)&As[k][ty * 8 + 4];
            float4 b0 = *(const float4*)&Ws[k][tx * 8];
            float4 b1 = *(const float4*)&Ws[k][tx * 8 + 4];
            float a[8] = {a0.x, a0.y, a0.z, a0.w, a1.x, a1.y, a1.z, a1.w};
            float b[8] = {b0.x, b0.y, b0.z, b0.w, b1.x, b1.y, b1.z, b1.w};
#pragma unroll
            for (int i = 0; i < 8; i++)
#pragma unroll
                for (int j = 0; j < 8; j++) acc[i][j] += a[i] * b[j];
        }
    }

#pragma unroll
    for (int i = 0; i < 8; i++) {
        int gr = row0 + ty * 8 + i;
        if (gr >= M) continue;
#pragma unroll
        for (int j = 0; j < 8; j += 4) {
            int gc = col0 + tx * 8 + j;
            float4 v = make_float4(acc[i][j], acc[i][j + 1], acc[i][j + 2], acc[i][j + 3]);
            if (bias) {
                v.x += bias[gc]; v.y += bias[gc + 1];
                v.z += bias[gc + 2]; v.w += bias[gc + 3];
            }
            *(float4*)(C + (size_t)gr * N + gc) = v;
        }
    }
}

// C[M,N] = relu(A@W^T + Add[M,N] + bias) — SAGE layer with pre-aggregated term
__global__ __launch_bounds__(256) void gemm_add_kernel(
    const float* __restrict__ A, const float* __restrict__ W,
    const float* __restrict__ Add, const float* __restrict__ bias,
    float* __restrict__ C, int M, int N, int K)
{
    __shared__ float As[BK][BM];
    __shared__ float Ws[BK][BN];
    const int tid = threadIdx.x;
    const int row0 = blockIdx.x * BM, col0 = blockIdx.y * BN;
    const int tx = tid & 15, ty = tid >> 4;
    const int lr = tid >> 1;
    const int lk = (tid & 1) * 4;

    float acc[8][8];
#pragma unroll
    for (int i = 0; i < 8; i++)
#pragma unroll
        for (int j = 0; j < 8; j++) acc[i][j] = 0.f;

    const bool arow_ok = (row0 + lr) < M;
    const float* Ap = A + (size_t)(row0 + lr) * K + lk;
    const float* Wp = W + (size_t)(col0 + lr) * K + lk;

    for (int k0 = 0; k0 < K; k0 += BK) {
        float4 av = make_float4(0.f, 0.f, 0.f, 0.f);
        if (arow_ok) av = *(const float4*)(Ap + k0);
        float4 wv = *(const float4*)(Wp + k0);
        __syncthreads();
        As[lk + 0][lr] = av.x; As[lk + 1][lr] = av.y;
        As[lk + 2][lr] = av.z; As[lk + 3][lr] = av.w;
        Ws[lk + 0][lr] = wv.x; Ws[lk + 1][lr] = wv.y;
        Ws[lk + 2][lr] = wv.z; Ws[lk + 3][lr] = wv.w;
        __syncthreads();
#pragma unroll
        for (int k = 0; k < BK; k++) {
            float4 a0 = *(const float4*)&As[k][ty * 8];
            float4 a1 = *(const float4*)&As[k][ty * 8 + 4];
            float4 b0 = *(const float4*)&Ws[k][tx * 8];
            float4 b1 = *(const float4*)&Ws[k][tx * 8 + 4];
            float a[8] = {a0.x, a0.y, a0.z, a0.w, a1.x, a1.y, a1.z, a1.w};
            float b[8] = {b0.x, b0.y, b0.z, b0.w, b1.x, b1.y, b1.z, b1.w};
#pragma unroll
            for (int i = 0; i < 8; i++)
#pragma unroll
                for (int j = 0; j < 8; j++) acc[i][j] += a[i] * b[j];
        }
    }

#pragma unroll
    for (int i = 0; i < 8; i++) {
        int gr = row0 + ty * 8 + i;
        if (gr >= M) continue;
#pragma unroll
        for (int j = 0; j < 8; j += 4) {
            int gc = col0 + tx * 8 + j;
            float4 ad = *(const float4*)(Add + (size_t)gr * N + gc);
            float4 v = make_float4(acc[i][j], acc[i][j + 1], acc[i][j + 2], acc[i][j + 3]);
            v.x = fmaxf(v.x + ad.x + bias[gc], 0.f);
            v.y = fmaxf(v.y + ad.y + bias[gc + 1], 0.f);
            v.z = fmaxf(v.z + ad.z + bias[gc + 2], 0.f);
            v.w = fmaxf(v.w + ad.w + bias[gc + 3], 0.f);
            *(float4*)(C + (size_t)gr * N + gc) = v;
        }
    }
}

// C[M,N] = relu(A1@W1^T + A2@W2^T + bias) — fused SAGE layer (taxon dst)
__global__ __launch_bounds__(256) void gemm2_kernel(
    const float* __restrict__ A1, const float* __restrict__ W1, int K1,
    const float* __restrict__ A2, const float* __restrict__ W2, int K2,
    const float* __restrict__ bias, float* __restrict__ C,
    int M, int N)
{
    __shared__ float As[BK][BM];
    __shared__ float Ws[BK][BN];
    const int tid = threadIdx.x;
    const int row0 = blockIdx.x * BM, col0 = blockIdx.y * BN;
    const int tx = tid & 15, ty = tid >> 4;
    const int lr = tid >> 1;
    const int lk = (tid & 1) * 4;

    float acc[8][8];
#pragma unroll
    for (int i = 0; i < 8; i++)
#pragma unroll
        for (int j = 0; j < 8; j++) acc[i][j] = 0.f;

    const bool arow_ok = (row0 + lr) < M;

#pragma unroll 1
    for (int pass = 0; pass < 2; pass++) {
        const float* A = pass ? A2 : A1;
        const float* W = pass ? W2 : W1;
        const int K = pass ? K2 : K1;
        const float* Ap = A + (size_t)(row0 + lr) * K + lk;
        const float* Wp = W + (size_t)(col0 + lr) * K + lk;
        for (int k0 = 0; k0 < K; k0 += BK) {
            float4 av = make_float4(0.f, 0.f, 0.f, 0.f);
            if (arow_ok) av = *(const float4*)(Ap + k0);
            float4 wv = *(const float4*)(Wp + k0);
            __syncthreads();
            As[lk + 0][lr] = av.x; As[lk + 1][lr] = av.y;
            As[lk + 2][lr] = av.z; As[lk + 3][lr] = av.w;
            Ws[lk + 0][lr] = wv.x; Ws[lk + 1][lr] = wv.y;
            Ws[lk + 2][lr] = wv.z; Ws[lk + 3][lr] = wv.w;
            __syncthreads();
#pragma unroll
            for (int k = 0; k < BK; k++) {
                float4 a0 = *(const float4*)&As[k][ty * 8];
                float4 a1 = *(const float4*)&As[k][ty * 8 + 4];
                float4 b0 = *(const float4*)&Ws[k][tx * 8];
                float4 b1 = *(const float4*)&Ws[k][tx * 8 + 4];
                float a[8] = {a0.x, a0.y, a0.z, a0.w, a1.x, a1.y, a1.z, a1.w};
                float b[8] = {b0.x, b0.y, b0.z, b0.w, b1.x, b1.y, b1.z, b1.w};
#pragma unroll
                for (int i = 0; i < 8; i++)
#pragma unroll
                    for (int j = 0; j < 8; j++) acc[i][j] += a[i] * b[j];
            }
        }
    }

#pragma unroll
    for (int i = 0; i < 8; i++) {
        int gr = row0 + ty * 8 + i;
        if (gr >= M) continue;
#pragma unroll
        for (int j = 0; j < 8; j += 4) {
            int gc = col0 + tx * 8 + j;
            float4 v = make_float4(acc[i][j], acc[i][j + 1], acc[i][j + 2], acc[i][j + 3]);
            v.x = fmaxf(v.x + bias[gc], 0.f);
            v.y = fmaxf(v.y + bias[gc + 1], 0.f);
            v.z = fmaxf(v.z + bias[gc + 2], 0.f);
            v.w = fmaxf(v.w + bias[gc + 3], 0.f);
            *(float4*)(C + (size_t)gr * N + gc) = v;
        }
    }
}

// ------------------- decoder weight folding (one-off, tiny) ----------------
// C[256][256] = A[h][k] (lda stride) @ B[k][f]  (contract k=0..255)
__global__ void gemm_nn_kernel(const float* __restrict__ A, int lda,
                               const float* __restrict__ B, float* __restrict__ C)
{
    const int h = blockIdx.x;
    const int f = threadIdx.x;
    float s = 0.f;
    for (int k = 0; k < 256; k++) s += A[h * lda + k] * B[k * 256 + f];
    C[h * 256 + f] = s;
}

// bu[h] = bd1[h] + Wd1L[h]·blin_s ; bv[h] = Wd1R[h]·blin_t
__global__ void bias_prep_kernel(const float* __restrict__ Wd1,
                                 const float* __restrict__ bd1,
                                 const float* __restrict__ blin_s,
                                 const float* __restrict__ blin_t,
                                 float* __restrict__ bu, float* __restrict__ bv)
{
    const int h = threadIdx.x;
    float su = 0.f, sv = 0.f;
    for (int k = 0; k < 256; k++) {
        su += Wd1[h * 512 + k] * blin_s[k];
        sv += Wd1[h * 512 + 256 + k] * blin_t[k];
    }
    bu[h] = bd1[h] + su;
    bv[h] = sv;
}

// --------------------------- CSR build -------------------------------------
__global__ void count_kernel(const int* __restrict__ src, const int* __restrict__ dst,
                             int* __restrict__ cnt_s, int* __restrict__ cnt_t, int E)
{
    int e = blockIdx.x * blockDim.x + threadIdx.x;
    if (e < E) {
        atomicAdd(&cnt_s[src[e]], 1);
        atomicAdd(&cnt_t[dst[e]], 1);
    }
}

__global__ __launch_bounds__(256) void partial_sum_kernel(
    const int* __restrict__ cnt, int* __restrict__ bsum, int N)
{
    __shared__ int sdata[256];
    const int t = threadIdx.x;
    const int base = blockIdx.x * 1024;
    int s = 0;
    for (int i = t; i < 1024; i += 256) {
        int idx = base + i;
        s += (idx < N) ? cnt[idx] : 0;
    }
    sdata[t] = s; __syncthreads();
    for (int off = 128; off > 0; off >>= 1) {
        if (t < off) sdata[t] += sdata[t + off];
        __syncthreads();
    }
    if (t == 0) bsum[blockIdx.x] = sdata[0];
}

__global__ void scan_bsum_kernel(int* __restrict__ bsum, int nb)
{
    if (blockIdx.x == 0 && threadIdx.x == 0) {
        int run = 0;
        for (int i = 0; i < nb; i++) { int v = bsum[i]; bsum[i] = run; run += v; }
    }
}

__global__ __launch_bounds__(256) void scan_block_kernel(
    const int* __restrict__ cnt, const int* __restrict__ bsum,
    int* __restrict__ rowptr, int N)
{
    __shared__ int sc[256];
    const int t = threadIdx.x;
    const int base = blockIdx.x * 1024 + t * 4;
    int v[4]; int s = 0;
#pragma unroll
    for (int j = 0; j < 4; j++) {
        int idx = base + j;
        v[j] = (idx < N) ? cnt[idx] : 0;
        s += v[j];
    }
    sc[t] = s; __syncthreads();
    for (int off = 1; off < 256; off <<= 1) {
        int add = (t >= off) ? sc[t - off] : 0;
        __syncthreads();
        sc[t] += add;
        __syncthreads();
    }
    int excl = sc[t] - s + bsum[blockIdx.x];
#pragma unroll
    for (int j = 0; j < 4; j++) {
        int idx = base + j;
        if (idx < N) rowptr[idx] = excl;
        if (idx == N - 1) rowptr[N] = excl + v[j];
        excl += v[j];
    }
}

__global__ void copy_int_kernel(const int* __restrict__ a, int* __restrict__ b, int n)
{
    int i = blockIdx.x * blockDim.x + threadIdx.x;
    if (i < n) b[i] = a[i];
}

__global__ void fill_kernel(const int* __restrict__ src, const int* __restrict__ dst,
                            int* __restrict__ cur_s, int* __restrict__ cur_t,
                            int* __restrict__ col_s, int* __restrict__ col_t, int E)
{
    int e = blockIdx.x * blockDim.x + threadIdx.x;
    if (e < E) {
        int s = src[e], d = dst[e];
        int pt = atomicAdd(&cur_t[d], 1);
        col_t[pt] = s;
        int ps = atomicAdd(&cur_s[s], 1);
        col_s[ps] = d;
    }
}

// ----------------------- gather mean aggregation ---------------------------
__global__ __launch_bounds__(256) void gather_mean_kernel(
    const float* __restrict__ X, const int* __restrict__ rowptr,
    const int* __restrict__ col, float* __restrict__ out, int N, int D)
{
    const int tpn = D >> 2;
    const int npb = 256 / tpn;
    const int node = blockIdx.x * npb + threadIdx.x / tpn;
    const int c = (threadIdx.x % tpn) * 4;
    if (node >= N) return;
    const int beg = rowptr[node], end = rowptr[node + 1];
    float4 acc0 = make_float4(0.f, 0.f, 0.f, 0.f);
    float4 acc1 = make_float4(0.f, 0.f, 0.f, 0.f);
    int i = beg;
    for (; i + 1 < end; i += 2) {
        int n0 = col[i], n1 = col[i + 1];
        float4 v0 = *(const float4*)&X[(size_t)n0 * D + c];
        float4 v1 = *(const float4*)&X[(size_t)n1 * D + c];
        acc0.x += v0.x; acc0.y += v0.y; acc0.z += v0.z; acc0.w += v0.w;
        acc1.x += v1.x; acc1.y += v1.y; acc1.z += v1.z; acc1.w += v1.w;
    }
    if (i < end) {
        float4 v0 = *(const float4*)&X[(size_t)col[i] * D + c];
        acc0.x += v0.x; acc0.y += v0.y; acc0.z += v0.z; acc0.w += v0.w;
    }
    float inv = 1.f / fmaxf((float)(end - beg), 1.f);
    float4 r;
    r.x = (acc0.x + acc1.x) * inv; r.y = (acc0.y + acc1.y) * inv;
    r.z = (acc0.z + acc1.z) * inv; r.w = (acc0.w + acc1.w) * inv;
    *(float4*)&out[(size_t)node * D + c] = r;
}

// ------------------------- per-edge score ----------------------------------
// out[e] = bd2 + Wd2 · relu(U[ls[e]] + V[ld[e]])   (one wave per edge)
__global__ __launch_bounds__(256) void edge_score_kernel(
    const float* __restrict__ U, const float* __restrict__ V,
    const int* __restrict__ ls, const int* __restrict__ ld,
    const float* __restrict__ Wd2, const float* __restrict__ bd2,
    float* __restrict__ out, int EL)
{
    const int wv = threadIdx.x >> 6, lane = threadIdx.x & 63;
    const int e = blockIdx.x * 4 + wv;
    if (e >= EL) return;
    const int c = lane * 4;
    float4 u = *(const float4*)&U[(size_t)ls[e] * 256 + c];
    float4 v = *(const float4*)&V[(size_t)ld[e] * 256 + c];
    float4 w = *(const float4*)&Wd2[c];
    float s = fmaxf(u.x + v.x, 0.f) * w.x + fmaxf(u.y + v.y, 0.f) * w.y
            + fmaxf(u.z + v.z, 0.f) * w.z + fmaxf(u.w + v.w, 0.f) * w.w;
#pragma unroll
    for (int m = 32; m >= 1; m >>= 1) s += __shfl_xor(s, m, 64);
    if (lane == 0) out[e] = s + bd2[0];
}

// ---------------------------------------------------------------------------
extern "C" void kernel_launch(void* const* d_in, const int* in_sizes, int n_in,
                              void* d_out, int out_size, void* d_ws, size_t ws_size,
                              hipStream_t stream)
{
    const float* x_sotu  = (const float*)d_in[0];
    const float* x_taxon = (const float*)d_in[1];
    const int* edge_src  = (const int*)d_in[2];
    const int* edge_dst  = (const int*)d_in[3];
    const int* label_src = (const int*)d_in[4];
    const int* label_dst = (const int*)d_in[5];
    const float* Wl1_st = (const float*)d_in[6];
    const float* bl1_st = (const float*)d_in[7];
    const float* Wr1_st = (const float*)d_in[8];
    const float* Wl1_ts = (const float*)d_in[9];
    const float* bl1_ts = (const float*)d_in[10];
    const float* Wr1_ts = (const float*)d_in[11];
    const float* Wl2_st = (const float*)d_in[12];
    const float* bl2_st = (const float*)d_in[13];
    const float* Wr2_st = (const float*)d_in[14];
    const float* Wl2_ts = (const float*)d_in[15];
    const float* bl2_ts = (const float*)d_in[16];
    const float* Wr2_ts = (const float*)d_in[17];
    const float* Wlin_s = (const float*)d_in[18];
    const float* blin_s = (const float*)d_in[19];
    const float* Wlin_t = (const float*)d_in[20];
    const float* blin_t = (const float*)d_in[21];
    const float* Wd1 = (const float*)d_in[22];
    const float* bd1 = (const float*)d_in[23];
    const float* Wd2 = (const float*)d_in[24];
    const float* bd2 = (const float*)d_in[25];

    // -------- workspace layout --------
    int* wi = (int*)d_ws;
    size_t io = 0;
    int* cnt_s   = wi + io; io += NS;
    int* cnt_t   = wi + io; io += NT;
    int* rowptr_s = wi + io; io += NS + 4;
    int* rowptr_t = wi + io; io += NT + 4;
    int* cur_s   = wi + io; io += NS;
    int* cur_t   = wi + io; io += NT;
    int* col_s   = wi + io; io += E_EDGES;
    int* col_t   = wi + io; io += E_EDGES;
    int* bsum_s  = wi + io; io += 128;
    int* bsum_t  = wi + io; io += 128;
    io = (io + 3) & ~(size_t)3;

    float* ws = (float*)(wi + io);
    size_t o = 0;
    float* m_s  = ws + o; o += (size_t)NS * H;   // agg(sotu dst); later U
    float* m_t  = ws + o; o += (size_t)NT * H;   // agg(taxon dst); later V
    float* h1_s = ws + o; o += (size_t)NS * H;
    float* h1_t = ws + o; o += (size_t)NT * H;
    float* h2_s = ws + o; o += (size_t)NS * H;   // also scratch for P1t/P2t
    float* h2_t = ws + o; o += (size_t)NT * H;
    float* Wc_s = ws + o; o += 256 * 256;
    float* Wc_t = ws + o; o += 256 * 256;
    float* bu   = ws + o; o += 256;
    float* bv   = ws + o; o += 256;
    float* Pt   = h2_s;   // 20k x 256 projected-taxon scratch (h2_s free till L2)
    float* U    = m_s;    // reuse (agg dead after gemm_add consumes it)
    float* V    = m_t;

    const dim3 blk(256);
    auto grd = [](int M) { return dim3((M + BM - 1) / BM, H / BN); };
    const int nbS = (NS + 1023) / 1024;
    const int nbT = (NT + 1023) / 1024;

    // ---- decoder weight folding (independent of everything) ----
    gemm_nn_kernel<<<256, blk, 0, stream>>>(Wd1, 512, Wlin_s, Wc_s);
    gemm_nn_kernel<<<256, blk, 0, stream>>>(Wd1 + 256, 512, Wlin_t, Wc_t);
    bias_prep_kernel<<<1, blk, 0, stream>>>(Wd1, bd1, blin_s, blin_t, bu, bv);

    // ---- CSR build (both directions) ----
    hipMemsetAsync(cnt_s, 0, (size_t)(NS + NT) * sizeof(int), stream);
    count_kernel<<<(E_EDGES + 255) / 256, blk, 0, stream>>>(edge_src, edge_dst,
                                                            cnt_s, cnt_t, E_EDGES);
    partial_sum_kernel<<<nbS, blk, 0, stream>>>(cnt_s, bsum_s, NS);
    partial_sum_kernel<<<nbT, blk, 0, stream>>>(cnt_t, bsum_t, NT);
    scan_bsum_kernel<<<1, 64, 0, stream>>>(bsum_s, nbS);
    scan_bsum_kernel<<<1, 64, 0, stream>>>(bsum_t, nbT);
    scan_block_kernel<<<nbS, blk, 0, stream>>>(cnt_s, bsum_s, rowptr_s, NS);
    scan_block_kernel<<<nbT, blk, 0, stream>>>(cnt_t, bsum_t, rowptr_t, NT);
    copy_int_kernel<<<(NS + 255) / 256, blk, 0, stream>>>(rowptr_s, cur_s, NS);
    copy_int_kernel<<<(NT + 255) / 256, blk, 0, stream>>>(rowptr_t, cur_t, NT);
    fill_kernel<<<(E_EDGES + 255) / 256, blk, 0, stream>>>(
        edge_src, edge_dst, cur_s, cur_t, col_s, col_t, E_EDGES);

    // ---- layer 1 ----
    // P1t = x_taxon @ Wl1_ts^T (project 20k rows BEFORE aggregating to 100k)
    gemm_kernel<<<grd(NT), blk, 0, stream>>>(x_taxon, Wl1_ts, nullptr, Pt, NT, H, DT);
    gather_mean_kernel<<<(NT * 64 + 255) / 256, blk, 0, stream>>>(
        x_sotu, rowptr_t, col_t, m_t, NT, DS);          // taxon dst: raw sotu feats
    gather_mean_kernel<<<(NS * 64 + 255) / 256, blk, 0, stream>>>(
        Pt, rowptr_s, col_s, m_s, NS, H);               // sotu dst: projected rows
    gemm2_kernel<<<grd(NT), blk, 0, stream>>>(m_t, Wl1_st, 256,
                                              x_taxon, Wr1_st, 128,
                                              bl1_st, h1_t, NT, H);
    gemm_add_kernel<<<grd(NS), blk, 0, stream>>>(x_sotu, Wr1_ts, m_s,
                                                 bl1_ts, h1_s, NS, H, DS);

    // ---- layer 2 ----
    gemm_kernel<<<grd(NT), blk, 0, stream>>>(h1_t, Wl2_ts, nullptr, Pt, NT, H, H);
    gather_mean_kernel<<<(NT * 64 + 255) / 256, blk, 0, stream>>>(
        h1_s, rowptr_t, col_t, m_t, NT, H);
    gather_mean_kernel<<<(NS * 64 + 255) / 256, blk, 0, stream>>>(
        Pt, rowptr_s, col_s, m_s, NS, H);
    gemm2_kernel<<<grd(NT), blk, 0, stream>>>(m_t, Wl2_st, 256,
                                              h1_t, Wr2_st, 256,
                                              bl2_st, h2_t, NT, H);
    gemm_add_kernel<<<grd(NS), blk, 0, stream>>>(h1_s, Wr2_ts, m_s,
                                                 bl2_ts, h2_s, NS, H, H);

    // ---- decoder: U/V node potentials + per-edge reduce ----
    gemm_kernel<<<grd(NS), blk, 0, stream>>>(h2_s, Wc_s, bu, U, NS, H, H);
    gemm_kernel<<<grd(NT), blk, 0, stream>>>(h2_t, Wc_t, bv, V, NT, H, H);
    edge_score_kernel<<<(EL_EDGES + 3) / 4, blk, 0, stream>>>(
        U, V, label_src, label_dst, Wd2, bd2, (float*)d_out, EL_EDGES);
}

// Round 6
// 1161.652 us; speedup vs baseline: 10.8503x; 1.6130x over previous
//
#include <hip/hip_runtime.h>

// ---------------------------------------------------------------------------
// Hetero GraphSAGE (2 layers) + edge decoder.
// R1: CSR-gather aggregation. R2/R3: register-blocked decoder GEMM.
// R4: algebraic restructure (decoder split U/V + weight folding;
//     project-before-aggregate). GEMM FLOP 1.23e11 -> 5.3e10.
// R5: all GEMMs -> bf16 MFMA (mfma_f32_16x16x32_bf16, fp32 accum);
//     activations stored bf16 (halves gather traffic). fp32 vector GEMM was
//     at its issue floor (209us/dispatch, VALUBusy 48%, 4-way B-read LDS
//     conflicts). U/V + edge reduce stay fp32.
// ---------------------------------------------------------------------------

constexpr int NS = 100000, NT = 20000;
constexpr int E_EDGES = 800000, EL_EDGES = 200000;
constexpr int DS = 256, DT = 128, H = 256;

typedef __attribute__((ext_vector_type(8))) short short8;
typedef __attribute__((ext_vector_type(4))) float float4v;
typedef unsigned short ushort_t;

__device__ __forceinline__ float bf2f(unsigned int u) {
    union { unsigned int i; float f; } x; x.i = u << 16; return x.f;
}
__device__ __forceinline__ unsigned short f2bf(float f) {
    union { float f; unsigned int i; } x; x.f = f;
    unsigned int r = x.i + 0x7FFFu + ((x.i >> 16) & 1u);   // RNE
    return (unsigned short)(r >> 16);
}

// --------------------------- MFMA GEMM -------------------------------------
// C[M,256] = op( A1@W1^T [+ A2@W2^T] [+ Add] [+ bias] ), op = relu?
// A,W bf16 row-major (W is [N][K] i.e. B^T form); 128x128 tile, BK=32.
// Fragments (HW-verified m89/m91/m97): A/W row-frag [lane&15][quad*8+j],
// C/D col=lane&15, row=quad*4+reg. LDS stride 40 ushorts: frag reads land
// 2 lanes per 4-bank group = b128 2-cycle floor (conflict-free).
// flags: 1 = relu, 2 = fp32 output
__global__ __launch_bounds__(256) void mgemm_kernel(
    const ushort_t* __restrict__ A1, const ushort_t* __restrict__ W1, int K1,
    const ushort_t* __restrict__ A2, const ushort_t* __restrict__ W2, int K2,
    const ushort_t* __restrict__ Add, const float* __restrict__ bias,
    void* __restrict__ Cout, int M, int flags)
{
    __shared__ ushort_t As[128][40];
    __shared__ ushort_t Bs[128][40];
    const int tid = threadIdx.x;
    const int row0 = blockIdx.x * 128, col0 = blockIdx.y * 128;
    const int wave = tid >> 6, lane = tid & 63;
    const int wrow = (wave >> 1) * 64, wcol = (wave & 1) * 64;
    const int m16 = lane & 15, quad = lane >> 4;
    const int sr = tid >> 2;                 // staging row 0..63 (and +64)
    const int skc = (tid & 3) * 8;           // k-chunk 0,8,16,24

    float4v acc[4][4];
#pragma unroll
    for (int i = 0; i < 4; i++)
#pragma unroll
        for (int j = 0; j < 4; j++) acc[i][j] = (float4v){0.f, 0.f, 0.f, 0.f};

#pragma unroll 1
    for (int pass = 0; pass < 2; pass++) {
        const ushort_t* A = pass ? A2 : A1;
        const ushort_t* W = pass ? W2 : W1;
        const int K = pass ? K2 : K1;
        if (!A) break;
        const int gr0 = row0 + sr, gr1 = row0 + sr + 64;
        const bool ok0 = gr0 < M, ok1 = gr1 < M;
        for (int k0 = 0; k0 < K; k0 += 32) {
            uint4 a0 = make_uint4(0, 0, 0, 0), a1 = make_uint4(0, 0, 0, 0);
            if (ok0) a0 = *(const uint4*)&A[(size_t)gr0 * K + k0 + skc];
            if (ok1) a1 = *(const uint4*)&A[(size_t)gr1 * K + k0 + skc];
            uint4 b0 = *(const uint4*)&W[(size_t)(col0 + sr) * K + k0 + skc];
            uint4 b1 = *(const uint4*)&W[(size_t)(col0 + sr + 64) * K + k0 + skc];
            __syncthreads();
            *(uint4*)&As[sr][skc] = a0;
            *(uint4*)&As[sr + 64][skc] = a1;
            *(uint4*)&Bs[sr][skc] = b0;
            *(uint4*)&Bs[sr + 64][skc] = b1;
            __syncthreads();
            short8 af[4], bf[4];
#pragma unroll
            for (int i = 0; i < 4; i++)
                af[i] = *(const short8*)&As[wrow + i * 16 + m16][quad * 8];
#pragma unroll
            for (int j = 0; j < 4; j++)
                bf[j] = *(const short8*)&Bs[wcol + j * 16 + m16][quad * 8];
#pragma unroll
            for (int i = 0; i < 4; i++)
#pragma unroll
                for (int j = 0; j < 4; j++)
                    acc[i][j] = __builtin_amdgcn_mfma_f32_16x16x32_bf16(
                        af[i], bf[j], acc[i][j], 0, 0, 0);
        }
    }

    const bool relu = flags & 1, f32out = flags & 2;
#pragma unroll
    for (int i = 0; i < 4; i++) {
        const int rbase = row0 + wrow + i * 16 + quad * 4;
#pragma unroll
        for (int r = 0; r < 4; r++) {
            const int row = rbase + r;
            if (row >= M) continue;
#pragma unroll
            for (int j = 0; j < 4; j++) {
                const int col = col0 + wcol + j * 16 + m16;
                float v = acc[i][j][r];
                if (Add) v += bf2f((unsigned int)Add[(size_t)row * 256 + col]);
                if (bias) v += bias[col];
                if (relu) v = fmaxf(v, 0.f);
                if (f32out) ((float*)Cout)[(size_t)row * 256 + col] = v;
                else ((ushort_t*)Cout)[(size_t)row * 256 + col] = f2bf(v);
            }
        }
    }
}

// --------------------- batched fp32 -> bf16 convert ------------------------
struct CvtJobs {
    const float* src[14];
    ushort_t* dst[14];
    int n4[14];
    int cnt;
};

__global__ __launch_bounds__(256) void cvt_kernel(CvtJobs jb, int total4)
{
    int t = blockIdx.x * blockDim.x + threadIdx.x;
    if (t >= total4) return;
    int idx = t;
    for (int k = 0; k < jb.cnt; k++) {
        if (idx < jb.n4[k]) {
            float4 v = ((const float4*)jb.src[k])[idx];
            uint2 o;
            o.x = (unsigned int)f2bf(v.x) | ((unsigned int)f2bf(v.y) << 16);
            o.y = (unsigned int)f2bf(v.z) | ((unsigned int)f2bf(v.w) << 16);
            *(uint2*)(jb.dst[k] + (size_t)idx * 4) = o;
            return;
        }
        idx -= jb.n4[k];
    }
}

// ------------------- decoder weight folding (fp32, tiny) -------------------
__global__ void gemm_nn_kernel(const float* __restrict__ A, int lda,
                               const float* __restrict__ B, float* __restrict__ C)
{
    const int h = blockIdx.x;
    const int f = threadIdx.x;
    float s = 0.f;
    for (int k = 0; k < 256; k++) s += A[h * lda + k] * B[k * 256 + f];
    C[h * 256 + f] = s;
}

__global__ void bias_prep_kernel(const float* __restrict__ Wd1,
                                 const float* __restrict__ bd1,
                                 const float* __restrict__ blin_s,
                                 const float* __restrict__ blin_t,
                                 float* __restrict__ bu, float* __restrict__ bv)
{
    const int h = threadIdx.x;
    float su = 0.f, sv = 0.f;
    for (int k = 0; k < 256; k++) {
        su += Wd1[h * 512 + k] * blin_s[k];
        sv += Wd1[h * 512 + 256 + k] * blin_t[k];
    }
    bu[h] = bd1[h] + su;
    bv[h] = sv;
}

// --------------------------- CSR build -------------------------------------
__global__ void count_kernel(const int* __restrict__ src, const int* __restrict__ dst,
                             int* __restrict__ cnt_s, int* __restrict__ cnt_t, int E)
{
    int e = blockIdx.x * blockDim.x + threadIdx.x;
    if (e < E) {
        atomicAdd(&cnt_s[src[e]], 1);
        atomicAdd(&cnt_t[dst[e]], 1);
    }
}

__global__ __launch_bounds__(256) void partial_sum_kernel(
    const int* __restrict__ cnt, int* __restrict__ bsum, int N)
{
    __shared__ int sdata[256];
    const int t = threadIdx.x;
    const int base = blockIdx.x * 1024;
    int s = 0;
    for (int i = t; i < 1024; i += 256) {
        int idx = base + i;
        s += (idx < N) ? cnt[idx] : 0;
    }
    sdata[t] = s; __syncthreads();
    for (int off = 128; off > 0; off >>= 1) {
        if (t < off) sdata[t] += sdata[t + off];
        __syncthreads();
    }
    if (t == 0) bsum[blockIdx.x] = sdata[0];
}

__global__ void scan_bsum_kernel(int* __restrict__ bsum, int nb)
{
    if (blockIdx.x == 0 && threadIdx.x == 0) {
        int run = 0;
        for (int i = 0; i < nb; i++) { int v = bsum[i]; bsum[i] = run; run += v; }
    }
}

__global__ __launch_bounds__(256) void scan_block_kernel(
    const int* __restrict__ cnt, const int* __restrict__ bsum,
    int* __restrict__ rowptr, int N)
{
    __shared__ int sc[256];
    const int t = threadIdx.x;
    const int base = blockIdx.x * 1024 + t * 4;
    int v[4]; int s = 0;
#pragma unroll
    for (int j = 0; j < 4; j++) {
        int idx = base + j;
        v[j] = (idx < N) ? cnt[idx] : 0;
        s += v[j];
    }
    sc[t] = s; __syncthreads();
    for (int off = 1; off < 256; off <<= 1) {
        int add = (t >= off) ? sc[t - off] : 0;
        __syncthreads();
        sc[t] += add;
        __syncthreads();
    }
    int excl = sc[t] - s + bsum[blockIdx.x];
#pragma unroll
    for (int j = 0; j < 4; j++) {
        int idx = base + j;
        if (idx < N) rowptr[idx] = excl;
        if (idx == N - 1) rowptr[N] = excl + v[j];
        excl += v[j];
    }
}

__global__ void copy_int_kernel(const int* __restrict__ a, int* __restrict__ b, int n)
{
    int i = blockIdx.x * blockDim.x + threadIdx.x;
    if (i < n) b[i] = a[i];
}

__global__ void fill_kernel(const int* __restrict__ src, const int* __restrict__ dst,
                            int* __restrict__ cur_s, int* __restrict__ cur_t,
                            int* __restrict__ col_s, int* __restrict__ col_t, int E)
{
    int e = blockIdx.x * blockDim.x + threadIdx.x;
    if (e < E) {
        int s = src[e], d = dst[e];
        int pt = atomicAdd(&cur_t[d], 1);
        col_t[pt] = s;
        int ps = atomicAdd(&cur_s[s], 1);
        col_s[ps] = d;
    }
}

// ------------------- gather mean (bf16 rows, fp32 accum) -------------------
// D = 256 fixed. One wave per node; each lane handles 4 cols (8B).
__global__ __launch_bounds__(256) void gather_mean_kernel(
    const ushort_t* __restrict__ X, const int* __restrict__ rowptr,
    const int* __restrict__ col, ushort_t* __restrict__ out, int N)
{
    const int node = blockIdx.x * 4 + (threadIdx.x >> 6);
    const int c = (threadIdx.x & 63) * 4;
    if (node >= N) return;
    const int beg = rowptr[node], end = rowptr[node + 1];
    float a0 = 0, a1 = 0, a2 = 0, a3 = 0;
    float b0 = 0, b1 = 0, b2 = 0, b3 = 0;
    int i = beg;
    for (; i + 1 < end; i += 2) {
        uint2 v = *(const uint2*)&X[(size_t)col[i] * 256 + c];
        uint2 w = *(const uint2*)&X[(size_t)col[i + 1] * 256 + c];
        a0 += bf2f(v.x & 0xffff); a1 += bf2f(v.x >> 16);
        a2 += bf2f(v.y & 0xffff); a3 += bf2f(v.y >> 16);
        b0 += bf2f(w.x & 0xffff); b1 += bf2f(w.x >> 16);
        b2 += bf2f(w.y & 0xffff); b3 += bf2f(w.y >> 16);
    }
    if (i < end) {
        uint2 v = *(const uint2*)&X[(size_t)col[i] * 256 + c];
        a0 += bf2f(v.x & 0xffff); a1 += bf2f(v.x >> 16);
        a2 += bf2f(v.y & 0xffff); a3 += bf2f(v.y >> 16);
    }
    float inv = 1.f / fmaxf((float)(end - beg), 1.f);
    uint2 o;
    o.x = (unsigned int)f2bf((a0 + b0) * inv) | ((unsigned int)f2bf((a1 + b1) * inv) << 16);
    o.y = (unsigned int)f2bf((a2 + b2) * inv) | ((unsigned int)f2bf((a3 + b3) * inv) << 16);
    *(uint2*)&out[(size_t)node * 256 + c] = o;
}

// ------------------------- per-edge score (fp32) ---------------------------
__global__ __launch_bounds__(256) void edge_score_kernel(
    const float* __restrict__ U, const float* __restrict__ V,
    const int* __restrict__ ls, const int* __restrict__ ld,
    const float* __restrict__ Wd2, const float* __restrict__ bd2,
    float* __restrict__ out, int EL)
{
    const int wv = threadIdx.x >> 6, lane = threadIdx.x & 63;
    const int e = blockIdx.x * 4 + wv;
    if (e >= EL) return;
    const int c = lane * 4;
    float4 u = *(const float4*)&U[(size_t)ls[e] * 256 + c];
    float4 v = *(const float4*)&V[(size_t)ld[e] * 256 + c];
    float4 w = *(const float4*)&Wd2[c];
    float s = fmaxf(u.x + v.x, 0.f) * w.x + fmaxf(u.y + v.y, 0.f) * w.y
            + fmaxf(u.z + v.z, 0.f) * w.z + fmaxf(u.w + v.w, 0.f) * w.w;
#pragma unroll
    for (int m = 32; m >= 1; m >>= 1) s += __shfl_xor(s, m, 64);
    if (lane == 0) out[e] = s + bd2[0];
}

// ---------------------------------------------------------------------------
extern "C" void kernel_launch(void* const* d_in, const int* in_sizes, int n_in,
                              void* d_out, int out_size, void* d_ws, size_t ws_size,
                              hipStream_t stream)
{
    const float* x_sotu  = (const float*)d_in[0];
    const float* x_taxon = (const float*)d_in[1];
    const int* edge_src  = (const int*)d_in[2];
    const int* edge_dst  = (const int*)d_in[3];
    const int* label_src = (const int*)d_in[4];
    const int* label_dst = (const int*)d_in[5];
    const float* Wl1_st = (const float*)d_in[6];
    const float* bl1_st = (const float*)d_in[7];
    const float* Wr1_st = (const float*)d_in[8];
    const float* Wl1_ts = (const float*)d_in[9];
    const float* bl1_ts = (const float*)d_in[10];
    const float* Wr1_ts = (const float*)d_in[11];
    const float* Wl2_st = (const float*)d_in[12];
    const float* bl2_st = (const float*)d_in[13];
    const float* Wr2_st = (const float*)d_in[14];
    const float* Wl2_ts = (const float*)d_in[15];
    const float* bl2_ts = (const float*)d_in[16];
    const float* Wr2_ts = (const float*)d_in[17];
    const float* Wlin_s = (const float*)d_in[18];
    const float* blin_s = (const float*)d_in[19];
    const float* Wlin_t = (const float*)d_in[20];
    const float* blin_t = (const float*)d_in[21];
    const float* Wd1 = (const float*)d_in[22];
    const float* bd1 = (const float*)d_in[23];
    const float* Wd2 = (const float*)d_in[24];
    const float* bd2 = (const float*)d_in[25];

    // -------- workspace layout --------
    int* wi = (int*)d_ws;
    size_t io = 0;
    int* cnt_s   = wi + io; io += NS;
    int* cnt_t   = wi + io; io += NT;
    int* rowptr_s = wi + io; io += NS + 4;
    int* rowptr_t = wi + io; io += NT + 4;
    int* cur_s   = wi + io; io += NS;
    int* cur_t   = wi + io; io += NT;
    int* col_s   = wi + io; io += E_EDGES;
    int* col_t   = wi + io; io += E_EDGES;
    int* bsum_s  = wi + io; io += 128;
    int* bsum_t  = wi + io; io += 128;
    io = (io + 63) & ~(size_t)63;           // 256B-align

    // bf16 region (all sizes multiples of 256 elems -> 16B aligned)
    ushort_t* wb = (ushort_t*)(wi + io);
    size_t bo = 0;
    ushort_t* m_s  = wb + bo; bo += (size_t)NS * H;   // | U overlays m_s..h1_s
    ushort_t* h1_s = wb + bo; bo += (size_t)NS * H;   // |
    ushort_t* m_t  = wb + bo; bo += (size_t)NT * H;   // | V overlays m_t..h1_t
    ushort_t* h1_t = wb + bo; bo += (size_t)NT * H;   // |
    ushort_t* h2_s = wb + bo; bo += (size_t)NS * H;
    ushort_t* h2_t = wb + bo; bo += (size_t)NT * H;
    ushort_t* xs_b = wb + bo; bo += (size_t)NS * DS;
    ushort_t* xt_b = wb + bo; bo += (size_t)NT * DT;
    ushort_t* Pt   = wb + bo; bo += (size_t)NT * H;
    ushort_t* wb_l1st = wb + bo; bo += H * DS;
    ushort_t* wb_r1st = wb + bo; bo += H * DT;
    ushort_t* wb_l1ts = wb + bo; bo += H * DT;
    ushort_t* wb_r1ts = wb + bo; bo += H * DS;
    ushort_t* wb_l2st = wb + bo; bo += H * H;
    ushort_t* wb_r2st = wb + bo; bo += H * H;
    ushort_t* wb_l2ts = wb + bo; bo += H * H;
    ushort_t* wb_r2ts = wb + bo; bo += H * H;
    ushort_t* wcb_s   = wb + bo; bo += H * H;
    ushort_t* wcb_t   = wb + bo; bo += H * H;
    bo = (bo + 7) & ~(size_t)7;

    float* wf = (float*)(wb + bo);
    size_t fo = 0;
    float* Wc_s = wf + fo; fo += H * H;
    float* Wc_t = wf + fo; fo += H * H;
    float* bu   = wf + fo; fo += 256;
    float* bv   = wf + fo; fo += 256;

    float* U = (float*)m_s;   // NS*256 fp32 == 2 x NS*256 bf16 (m_s+h1_s) exactly
    float* V = (float*)m_t;   // NT*256 fp32 == m_t+h1_t

    const dim3 blk(256);
    auto mg = [](int M) { return dim3((M + 127) / 128, 2); };
    const int nbS = (NS + 1023) / 1024;
    const int nbT = (NT + 1023) / 1024;

    // ---- decoder weight folding (fp32) ----
    gemm_nn_kernel<<<256, blk, 0, stream>>>(Wd1, 512, Wlin_s, Wc_s);
    gemm_nn_kernel<<<256, blk, 0, stream>>>(Wd1 + 256, 512, Wlin_t, Wc_t);
    bias_prep_kernel<<<1, blk, 0, stream>>>(Wd1, bd1, blin_s, blin_t, bu, bv);

    // ---- batched fp32->bf16 conversion (inputs + weights + folded Wc) ----
    {
        CvtJobs jb; int c = 0, total4 = 0;
        auto addj = [&](const float* s, ushort_t* d, int n) {
            jb.src[c] = s; jb.dst[c] = d; jb.n4[c] = n / 4; total4 += n / 4; c++;
        };
        addj(x_sotu, xs_b, NS * DS);
        addj(x_taxon, xt_b, NT * DT);
        addj(Wl1_st, wb_l1st, H * DS);
        addj(Wr1_st, wb_r1st, H * DT);
        addj(Wl1_ts, wb_l1ts, H * DT);
        addj(Wr1_ts, wb_r1ts, H * DS);
        addj(Wl2_st, wb_l2st, H * H);
        addj(Wr2_st, wb_r2st, H * H);
        addj(Wl2_ts, wb_l2ts, H * H);
        addj(Wr2_ts, wb_r2ts, H * H);
        addj(Wc_s, wcb_s, H * H);
        addj(Wc_t, wcb_t, H * H);
        jb.cnt = c;
        cvt_kernel<<<(total4 + 255) / 256, blk, 0, stream>>>(jb, total4);
    }

    // ---- CSR build (both directions) ----
    hipMemsetAsync(cnt_s, 0, (size_t)(NS + NT) * sizeof(int), stream);
    count_kernel<<<(E_EDGES + 255) / 256, blk, 0, stream>>>(edge_src, edge_dst,
                                                            cnt_s, cnt_t, E_EDGES);
    partial_sum_kernel<<<nbS, blk, 0, stream>>>(cnt_s, bsum_s, NS);
    partial_sum_kernel<<<nbT, blk, 0, stream>>>(cnt_t, bsum_t, NT);
    scan_bsum_kernel<<<1, 64, 0, stream>>>(bsum_s, nbS);
    scan_bsum_kernel<<<1, 64, 0, stream>>>(bsum_t, nbT);
    scan_block_kernel<<<nbS, blk, 0, stream>>>(cnt_s, bsum_s, rowptr_s, NS);
    scan_block_kernel<<<nbT, blk, 0, stream>>>(cnt_t, bsum_t, rowptr_t, NT);
    copy_int_kernel<<<(NS + 255) / 256, blk, 0, stream>>>(rowptr_s, cur_s, NS);
    copy_int_kernel<<<(NT + 255) / 256, blk, 0, stream>>>(rowptr_t, cur_t, NT);
    fill_kernel<<<(E_EDGES + 255) / 256, blk, 0, stream>>>(
        edge_src, edge_dst, cur_s, cur_t, col_s, col_t, E_EDGES);

    // ---- layer 1 ----
    // Pt = x_taxon @ Wl1_ts^T (project 20k rows BEFORE aggregating to 100k)
    mgemm_kernel<<<mg(NT), blk, 0, stream>>>(xt_b, wb_l1ts, DT, nullptr, nullptr, 0,
                                             nullptr, nullptr, Pt, NT, 0);
    gather_mean_kernel<<<(NT + 3) / 4, blk, 0, stream>>>(xs_b, rowptr_t, col_t, m_t, NT);
    gather_mean_kernel<<<(NS + 3) / 4, blk, 0, stream>>>(Pt, rowptr_s, col_s, m_s, NS);
    // h1_t = relu(m_t@Wl1_st^T + x_taxon@Wr1_st^T + b)
    mgemm_kernel<<<mg(NT), blk, 0, stream>>>(m_t, wb_l1st, H, xt_b, wb_r1st, DT,
                                             nullptr, bl1_st, h1_t, NT, 1);
    // h1_s = relu(x_sotu@Wr1_ts^T + m_s + b)
    mgemm_kernel<<<mg(NS), blk, 0, stream>>>(xs_b, wb_r1ts, DS, nullptr, nullptr, 0,
                                             m_s, bl1_ts, h1_s, NS, 1);

    // ---- layer 2 ----
    mgemm_kernel<<<mg(NT), blk, 0, stream>>>(h1_t, wb_l2ts, H, nullptr, nullptr, 0,
                                             nullptr, nullptr, Pt, NT, 0);
    gather_mean_kernel<<<(NT + 3) / 4, blk, 0, stream>>>(h1_s, rowptr_t, col_t, m_t, NT);
    gather_mean_kernel<<<(NS + 3) / 4, blk, 0, stream>>>(Pt, rowptr_s, col_s, m_s, NS);
    mgemm_kernel<<<mg(NT), blk, 0, stream>>>(m_t, wb_l2st, H, h1_t, wb_r2st, H,
                                             nullptr, bl2_st, h2_t, NT, 1);
    mgemm_kernel<<<mg(NS), blk, 0, stream>>>(h1_s, wb_r2ts, H, nullptr, nullptr, 0,
                                             m_s, bl2_ts, h2_s, NS, 1);

    // ---- decoder: U/V node potentials (fp32 out) + per-edge reduce ----
    mgemm_kernel<<<mg(NS), blk, 0, stream>>>(h2_s, wcb_s, H, nullptr, nullptr, 0,
                                             nullptr, bu, U, NS, 2);
    mgemm_kernel<<<mg(NT), blk, 0, stream>>>(h2_t, wcb_t, H, nullptr, nullptr, 0,
                                             nullptr, bv, V, NT, 2);
    edge_score_kernel<<<(EL_EDGES + 3) / 4, blk, 0, stream>>>(
        U, V, label_src, label_dst, Wd2, bd2, (float*)d_out, EL_EDGES);
}

// Round 7
// 1116.656 us; speedup vs baseline: 11.2876x; 1.0403x over previous
//
#include <hip/hip_runtime.h>

// ---------------------------------------------------------------------------
// Hetero GraphSAGE (2 layers) + edge decoder.
// R1: CSR-gather aggregation. R4: algebraic restructure (U/V decoder split,
//     weight folding, project-before-aggregate). FLOP 1.23e11 -> 5.3e10.
// R5: bf16 MFMA GEMMs + bf16 activations. 1874 -> 1162 us.
// R6: fp16 U/V (halves edge_score gather + U write; err +~2e-4);
//     fill atomics directly on rowptr (cursor copy deleted);
//     fused CSR-aux + weight-fold kernels (26 -> 21 launches);
//     nontemporal col stores in fill.
// ---------------------------------------------------------------------------

constexpr int NS = 100000, NT = 20000;
constexpr int E_EDGES = 800000, EL_EDGES = 200000;
constexpr int DS = 256, DT = 128, H = 256;

typedef __attribute__((ext_vector_type(8))) short short8;
typedef __attribute__((ext_vector_type(4))) float float4v;
typedef __attribute__((ext_vector_type(4))) _Float16 half4v;
typedef unsigned short ushort_t;

__device__ __forceinline__ float bf2f(unsigned int u) {
    union { unsigned int i; float f; } x; x.i = u << 16; return x.f;
}
__device__ __forceinline__ unsigned short f2bf(float f) {
    union { float f; unsigned int i; } x; x.f = f;
    unsigned int r = x.i + 0x7FFFu + ((x.i >> 16) & 1u);   // RNE
    return (unsigned short)(r >> 16);
}

// --------------------------- MFMA GEMM -------------------------------------
// C[M,256] = op( A1@W1^T [+ A2@W2^T] [+ Add] [+ bias] )
// A,W bf16 row-major (W is [N][K] B^T form); 128x128 tile, BK=32.
// LDS stride 40 ushorts keeps b128 frag reads conflict-free.
// flags: 1 = relu, 2 = fp16 output (else bf16)
__global__ __launch_bounds__(256) void mgemm_kernel(
    const ushort_t* __restrict__ A1, const ushort_t* __restrict__ W1, int K1,
    const ushort_t* __restrict__ A2, const ushort_t* __restrict__ W2, int K2,
    const ushort_t* __restrict__ Add, const float* __restrict__ bias,
    void* __restrict__ Cout, int M, int flags)
{
    __shared__ ushort_t As[128][40];
    __shared__ ushort_t Bs[128][40];
    const int tid = threadIdx.x;
    const int row0 = blockIdx.x * 128, col0 = blockIdx.y * 128;
    const int wave = tid >> 6, lane = tid & 63;
    const int wrow = (wave >> 1) * 64, wcol = (wave & 1) * 64;
    const int m16 = lane & 15, quad = lane >> 4;
    const int sr = tid >> 2;                 // staging row 0..63 (and +64)
    const int skc = (tid & 3) * 8;           // k-chunk 0,8,16,24

    float4v acc[4][4];
#pragma unroll
    for (int i = 0; i < 4; i++)
#pragma unroll
        for (int j = 0; j < 4; j++) acc[i][j] = (float4v){0.f, 0.f, 0.f, 0.f};

#pragma unroll 1
    for (int pass = 0; pass < 2; pass++) {
        const ushort_t* A = pass ? A2 : A1;
        const ushort_t* W = pass ? W2 : W1;
        const int K = pass ? K2 : K1;
        if (!A) break;
        const int gr0 = row0 + sr, gr1 = row0 + sr + 64;
        const bool ok0 = gr0 < M, ok1 = gr1 < M;
        for (int k0 = 0; k0 < K; k0 += 32) {
            uint4 a0 = make_uint4(0, 0, 0, 0), a1 = make_uint4(0, 0, 0, 0);
            if (ok0) a0 = *(const uint4*)&A[(size_t)gr0 * K + k0 + skc];
            if (ok1) a1 = *(const uint4*)&A[(size_t)gr1 * K + k0 + skc];
            uint4 b0 = *(const uint4*)&W[(size_t)(col0 + sr) * K + k0 + skc];
            uint4 b1 = *(const uint4*)&W[(size_t)(col0 + sr + 64) * K + k0 + skc];
            __syncthreads();
            *(uint4*)&As[sr][skc] = a0;
            *(uint4*)&As[sr + 64][skc] = a1;
            *(uint4*)&Bs[sr][skc] = b0;
            *(uint4*)&Bs[sr + 64][skc] = b1;
            __syncthreads();
            short8 af[4], bf[4];
#pragma unroll
            for (int i = 0; i < 4; i++)
                af[i] = *(const short8*)&As[wrow + i * 16 + m16][quad * 8];
#pragma unroll
            for (int j = 0; j < 4; j++)
                bf[j] = *(const short8*)&Bs[wcol + j * 16 + m16][quad * 8];
#pragma unroll
            for (int i = 0; i < 4; i++)
#pragma unroll
                for (int j = 0; j < 4; j++)
                    acc[i][j] = __builtin_amdgcn_mfma_f32_16x16x32_bf16(
                        af[i], bf[j], acc[i][j], 0, 0, 0);
        }
    }

    const bool relu = flags & 1, f16out = flags & 2;
#pragma unroll
    for (int i = 0; i < 4; i++) {
        const int rbase = row0 + wrow + i * 16 + quad * 4;
#pragma unroll
        for (int r = 0; r < 4; r++) {
            const int row = rbase + r;
            if (row >= M) continue;
#pragma unroll
            for (int j = 0; j < 4; j++) {
                const int col = col0 + wcol + j * 16 + m16;
                float v = acc[i][j][r];
                if (Add) v += bf2f((unsigned int)Add[(size_t)row * 256 + col]);
                if (bias) v += bias[col];
                if (relu) v = fmaxf(v, 0.f);
                if (f16out) ((_Float16*)Cout)[(size_t)row * 256 + col] = (_Float16)v;
                else ((ushort_t*)Cout)[(size_t)row * 256 + col] = f2bf(v);
            }
        }
    }
}

// --------------------- batched fp32 -> bf16 convert ------------------------
struct CvtJobs {
    const float* src[14];
    ushort_t* dst[14];
    int n4[14];
    int cnt;
};

__global__ __launch_bounds__(256) void cvt_kernel(CvtJobs jb, int total4)
{
    int t = blockIdx.x * blockDim.x + threadIdx.x;
    if (t >= total4) return;
    int idx = t;
    for (int k = 0; k < jb.cnt; k++) {
        if (idx < jb.n4[k]) {
            float4 v = ((const float4*)jb.src[k])[idx];
            uint2 o;
            o.x = (unsigned int)f2bf(v.x) | ((unsigned int)f2bf(v.y) << 16);
            o.y = (unsigned int)f2bf(v.z) | ((unsigned int)f2bf(v.w) << 16);
            *(uint2*)(jb.dst[k] + (size_t)idx * 4) = o;
            return;
        }
        idx -= jb.n4[k];
    }
}

// -------------- decoder weight folding (one fused kernel) ------------------
// blocks 0..255:   Wc_s[h][:] = Wd1L[h] @ Wlin_s
// blocks 256..511: Wc_t[h][:] = Wd1R[h] @ Wlin_t
// block 512:       bu[h] = bd1[h] + Wd1L[h]·blin_s ; bv[h] = Wd1R[h]·blin_t
__global__ __launch_bounds__(256) void fold_kernel(
    const float* __restrict__ Wd1, const float* __restrict__ bd1,
    const float* __restrict__ Wlin_s, const float* __restrict__ blin_s,
    const float* __restrict__ Wlin_t, const float* __restrict__ blin_t,
    float* __restrict__ Wc_s, float* __restrict__ Wc_t,
    float* __restrict__ bu, float* __restrict__ bv)
{
    const int b = blockIdx.x, t = threadIdx.x;
    if (b < 256) {
        float s = 0.f;
        for (int k = 0; k < 256; k++) s += Wd1[b * 512 + k] * Wlin_s[k * 256 + t];
        Wc_s[b * 256 + t] = s;
    } else if (b < 512) {
        const int h = b - 256;
        float s = 0.f;
        for (int k = 0; k < 256; k++) s += Wd1[h * 512 + 256 + k] * Wlin_t[k * 256 + t];
        Wc_t[h * 256 + t] = s;
    } else {
        float su = 0.f, sv = 0.f;
        for (int k = 0; k < 256; k++) {
            su += Wd1[t * 512 + k] * blin_s[k];
            sv += Wd1[t * 512 + 256 + k] * blin_t[k];
        }
        bu[t] = bd1[t] + su;
        bv[t] = sv;
    }
}

// --------------------------- CSR build -------------------------------------
__global__ void count_kernel(const int* __restrict__ src, const int* __restrict__ dst,
                             int* __restrict__ cnt_s, int* __restrict__ cnt_t, int E)
{
    int e = blockIdx.x * blockDim.x + threadIdx.x;
    if (e < E) {
        atomicAdd(&cnt_s[src[e]], 1);
        atomicAdd(&cnt_t[dst[e]], 1);
    }
}

// per-block (1024-elem) sums, both node types in one grid
__global__ __launch_bounds__(256) void psum_kernel(
    const int* __restrict__ cnt_s, const int* __restrict__ cnt_t,
    int* __restrict__ bsum_s, int* __restrict__ bsum_t, int nbS)
{
    const bool isS = (int)blockIdx.x < nbS;
    const int blk = isS ? blockIdx.x : blockIdx.x - nbS;
    const int N = isS ? NS : NT;
    const int* cnt = isS ? cnt_s : cnt_t;
    int* bsum = isS ? bsum_s : bsum_t;
    __shared__ int sdata[256];
    const int t = threadIdx.x;
    const int base = blk * 1024;
    int s = 0;
    for (int i = t; i < 1024; i += 256) {
        int idx = base + i;
        s += (idx < N) ? cnt[idx] : 0;
    }
    sdata[t] = s; __syncthreads();
    for (int off = 128; off > 0; off >>= 1) {
        if (t < off) sdata[t] += sdata[t + off];
        __syncthreads();
    }
    if (t == 0) bsum[blk] = sdata[0];
}

// exclusive scan of both bsum arrays (2 blocks, serial in thread 0)
__global__ void sbsum_kernel(int* __restrict__ bsum_s, int* __restrict__ bsum_t,
                             int nbS, int nbT)
{
    if (threadIdx.x != 0) return;
    int* b = blockIdx.x ? bsum_t : bsum_s;
    int nb = blockIdx.x ? nbT : nbS;
    int run = 0;
    for (int i = 0; i < nb; i++) { int v = b[i]; b[i] = run; run += v; }
}

// per-block exclusive scan + block offset -> rowptr[N], both types
__global__ __launch_bounds__(256) void sblock_kernel(
    const int* __restrict__ cnt_s, const int* __restrict__ cnt_t,
    const int* __restrict__ bsum_s, const int* __restrict__ bsum_t,
    int* __restrict__ rowptr_s, int* __restrict__ rowptr_t, int nbS)
{
    const bool isS = (int)blockIdx.x < nbS;
    const int blk = isS ? blockIdx.x : blockIdx.x - nbS;
    const int N = isS ? NS : NT;
    const int* cnt = isS ? cnt_s : cnt_t;
    const int* bsum = isS ? bsum_s : bsum_t;
    int* rowptr = isS ? rowptr_s : rowptr_t;
    __shared__ int sc[256];
    const int t = threadIdx.x;
    const int base = blk * 1024 + t * 4;
    int v[4]; int s = 0;
#pragma unroll
    for (int j = 0; j < 4; j++) {
        int idx = base + j;
        v[j] = (idx < N) ? cnt[idx] : 0;
        s += v[j];
    }
    sc[t] = s; __syncthreads();
    for (int off = 1; off < 256; off <<= 1) {
        int add = (t >= off) ? sc[t - off] : 0;
        __syncthreads();
        sc[t] += add;
        __syncthreads();
    }
    int excl = sc[t] - s + bsum[blk];
#pragma unroll
    for (int j = 0; j < 4; j++) {
        int idx = base + j;
        if (idx < N) rowptr[idx] = excl;
        excl += v[j];
    }
}

// fill via atomics DIRECTLY on rowptr (post-fill rowptr[n] = inclusive scan;
// gathers recover beg = rowptr[n] - cnt[n]). Nontemporal col stores.
__global__ void fill_kernel(const int* __restrict__ src, const int* __restrict__ dst,
                            int* __restrict__ rowptr_s, int* __restrict__ rowptr_t,
                            int* __restrict__ col_s, int* __restrict__ col_t, int E)
{
    int e = blockIdx.x * blockDim.x + threadIdx.x;
    if (e < E) {
        int s = src[e], d = dst[e];
        int pt = atomicAdd(&rowptr_t[d], 1);
        __builtin_nontemporal_store(s, &col_t[pt]);
        int ps = atomicAdd(&rowptr_s[s], 1);
        __builtin_nontemporal_store(d, &col_s[ps]);
    }
}

// ------------------- gather mean (bf16 rows, fp32 accum) -------------------
// end = rowptr[n] (inclusive after fill), beg = end - cnt[n].
__global__ __launch_bounds__(256) void gather_mean_kernel(
    const ushort_t* __restrict__ X, const int* __restrict__ rowptr,
    const int* __restrict__ cnt, const int* __restrict__ col,
    ushort_t* __restrict__ out, int N)
{
    const int node = blockIdx.x * 4 + (threadIdx.x >> 6);
    const int c = (threadIdx.x & 63) * 4;
    if (node >= N) return;
    const int end = rowptr[node];
    const int deg = cnt[node];
    const int beg = end - deg;
    float a0 = 0, a1 = 0, a2 = 0, a3 = 0;
    float b0 = 0, b1 = 0, b2 = 0, b3 = 0;
    int i = beg;
    for (; i + 1 < end; i += 2) {
        uint2 v = *(const uint2*)&X[(size_t)col[i] * 256 + c];
        uint2 w = *(const uint2*)&X[(size_t)col[i + 1] * 256 + c];
        a0 += bf2f(v.x & 0xffff); a1 += bf2f(v.x >> 16);
        a2 += bf2f(v.y & 0xffff); a3 += bf2f(v.y >> 16);
        b0 += bf2f(w.x & 0xffff); b1 += bf2f(w.x >> 16);
        b2 += bf2f(w.y & 0xffff); b3 += bf2f(w.y >> 16);
    }
    if (i < end) {
        uint2 v = *(const uint2*)&X[(size_t)col[i] * 256 + c];
        a0 += bf2f(v.x & 0xffff); a1 += bf2f(v.x >> 16);
        a2 += bf2f(v.y & 0xffff); a3 += bf2f(v.y >> 16);
    }
    float inv = 1.f / fmaxf((float)deg, 1.f);
    uint2 o;
    o.x = (unsigned int)f2bf((a0 + b0) * inv) | ((unsigned int)f2bf((a1 + b1) * inv) << 16);
    o.y = (unsigned int)f2bf((a2 + b2) * inv) | ((unsigned int)f2bf((a3 + b3) * inv) << 16);
    *(uint2*)&out[(size_t)node * 256 + c] = o;
}

// ------------------------- per-edge score (fp16 U/V) -----------------------
__global__ __launch_bounds__(256) void edge_score_kernel(
    const _Float16* __restrict__ U, const _Float16* __restrict__ V,
    const int* __restrict__ ls, const int* __restrict__ ld,
    const float* __restrict__ Wd2, const float* __restrict__ bd2,
    float* __restrict__ out, int EL)
{
    const int wv = threadIdx.x >> 6, lane = threadIdx.x & 63;
    const int e = blockIdx.x * 4 + wv;
    if (e >= EL) return;
    const int c = lane * 4;
    half4v u = *(const half4v*)&U[(size_t)ls[e] * 256 + c];
    half4v v = *(const half4v*)&V[(size_t)ld[e] * 256 + c];
    float4 w = *(const float4*)&Wd2[c];
    float s = fmaxf((float)u.x + (float)v.x, 0.f) * w.x
            + fmaxf((float)u.y + (float)v.y, 0.f) * w.y
            + fmaxf((float)u.z + (float)v.z, 0.f) * w.z
            + fmaxf((float)u.w + (float)v.w, 0.f) * w.w;
#pragma unroll
    for (int m = 32; m >= 1; m >>= 1) s += __shfl_xor(s, m, 64);
    if (lane == 0) out[e] = s + bd2[0];
}

// ---------------------------------------------------------------------------
extern "C" void kernel_launch(void* const* d_in, const int* in_sizes, int n_in,
                              void* d_out, int out_size, void* d_ws, size_t ws_size,
                              hipStream_t stream)
{
    const float* x_sotu  = (const float*)d_in[0];
    const float* x_taxon = (const float*)d_in[1];
    const int* edge_src  = (const int*)d_in[2];
    const int* edge_dst  = (const int*)d_in[3];
    const int* label_src = (const int*)d_in[4];
    const int* label_dst = (const int*)d_in[5];
    const float* Wl1_st = (const float*)d_in[6];
    const float* bl1_st = (const float*)d_in[7];
    const float* Wr1_st = (const float*)d_in[8];
    const float* Wl1_ts = (const float*)d_in[9];
    const float* bl1_ts = (const float*)d_in[10];
    const float* Wr1_ts = (const float*)d_in[11];
    const float* Wl2_st = (const float*)d_in[12];
    const float* bl2_st = (const float*)d_in[13];
    const float* Wr2_st = (const float*)d_in[14];
    const float* Wl2_ts = (const float*)d_in[15];
    const float* bl2_ts = (const float*)d_in[16];
    const float* Wr2_ts = (const float*)d_in[17];
    const float* Wlin_s = (const float*)d_in[18];
    const float* blin_s = (const float*)d_in[19];
    const float* Wlin_t = (const float*)d_in[20];
    const float* blin_t = (const float*)d_in[21];
    const float* Wd1 = (const float*)d_in[22];
    const float* bd1 = (const float*)d_in[23];
    const float* Wd2 = (const float*)d_in[24];
    const float* bd2 = (const float*)d_in[25];

    // -------- workspace layout --------
    int* wi = (int*)d_ws;
    size_t io = 0;
    int* cnt_s   = wi + io; io += NS;
    int* cnt_t   = wi + io; io += NT;
    int* rowptr_s = wi + io; io += NS + 4;
    int* rowptr_t = wi + io; io += NT + 4;
    int* col_s   = wi + io; io += E_EDGES;
    int* col_t   = wi + io; io += E_EDGES;
    int* bsum_s  = wi + io; io += 128;
    int* bsum_t  = wi + io; io += 128;
    io = (io + 63) & ~(size_t)63;           // 256B-align

    ushort_t* wb = (ushort_t*)(wi + io);
    size_t bo = 0;
    ushort_t* m_s  = wb + bo; bo += (size_t)NS * H;   // U (fp16) overlays m_s
    ushort_t* h1_s = wb + bo; bo += (size_t)NS * H;
    ushort_t* m_t  = wb + bo; bo += (size_t)NT * H;   // V (fp16) overlays m_t
    ushort_t* h1_t = wb + bo; bo += (size_t)NT * H;
    ushort_t* h2_s = wb + bo; bo += (size_t)NS * H;
    ushort_t* h2_t = wb + bo; bo += (size_t)NT * H;
    ushort_t* xs_b = wb + bo; bo += (size_t)NS * DS;
    ushort_t* xt_b = wb + bo; bo += (size_t)NT * DT;
    ushort_t* Pt   = wb + bo; bo += (size_t)NT * H;
    ushort_t* wb_l1st = wb + bo; bo += H * DS;
    ushort_t* wb_r1st = wb + bo; bo += H * DT;
    ushort_t* wb_l1ts = wb + bo; bo += H * DT;
    ushort_t* wb_r1ts = wb + bo; bo += H * DS;
    ushort_t* wb_l2st = wb + bo; bo += H * H;
    ushort_t* wb_r2st = wb + bo; bo += H * H;
    ushort_t* wb_l2ts = wb + bo; bo += H * H;
    ushort_t* wb_r2ts = wb + bo; bo += H * H;
    ushort_t* wcb_s   = wb + bo; bo += H * H;
    ushort_t* wcb_t   = wb + bo; bo += H * H;
    bo = (bo + 7) & ~(size_t)7;

    float* wf = (float*)(wb + bo);
    size_t fo = 0;
    float* Wc_s = wf + fo; fo += H * H;
    float* Wc_t = wf + fo; fo += H * H;
    float* bu   = wf + fo; fo += 256;
    float* bv   = wf + fo; fo += 256;

    _Float16* U = (_Float16*)m_s;   // NS*256 fp16 fits exactly in m_s
    _Float16* V = (_Float16*)m_t;

    const dim3 blk(256);
    auto mg = [](int M) { return dim3((M + 127) / 128, 2); };
    const int nbS = (NS + 1023) / 1024;   // 98
    const int nbT = (NT + 1023) / 1024;   // 20

    // ---- decoder weight folding (fused) ----
    fold_kernel<<<513, blk, 0, stream>>>(Wd1, bd1, Wlin_s, blin_s, Wlin_t, blin_t,
                                         Wc_s, Wc_t, bu, bv);

    // ---- batched fp32->bf16 conversion ----
    {
        CvtJobs jb; int c = 0, total4 = 0;
        auto addj = [&](const float* s, ushort_t* d, int n) {
            jb.src[c] = s; jb.dst[c] = d; jb.n4[c] = n / 4; total4 += n / 4; c++;
        };
        addj(x_sotu, xs_b, NS * DS);
        addj(x_taxon, xt_b, NT * DT);
        addj(Wl1_st, wb_l1st, H * DS);
        addj(Wr1_st, wb_r1st, H * DT);
        addj(Wl1_ts, wb_l1ts, H * DT);
        addj(Wr1_ts, wb_r1ts, H * DS);
        addj(Wl2_st, wb_l2st, H * H);
        addj(Wr2_st, wb_r2st, H * H);
        addj(Wl2_ts, wb_l2ts, H * H);
        addj(Wr2_ts, wb_r2ts, H * H);
        addj(Wc_s, wcb_s, H * H);
        addj(Wc_t, wcb_t, H * H);
        jb.cnt = c;
        cvt_kernel<<<(total4 + 255) / 256, blk, 0, stream>>>(jb, total4);
    }

    // ---- CSR build (both directions) ----
    hipMemsetAsync(cnt_s, 0, (size_t)(NS + NT) * sizeof(int), stream);
    count_kernel<<<(E_EDGES + 255) / 256, blk, 0, stream>>>(edge_src, edge_dst,
                                                            cnt_s, cnt_t, E_EDGES);
    psum_kernel<<<nbS + nbT, blk, 0, stream>>>(cnt_s, cnt_t, bsum_s, bsum_t, nbS);
    sbsum_kernel<<<2, 64, 0, stream>>>(bsum_s, bsum_t, nbS, nbT);
    sblock_kernel<<<nbS + nbT, blk, 0, stream>>>(cnt_s, cnt_t, bsum_s, bsum_t,
                                                 rowptr_s, rowptr_t, nbS);
    fill_kernel<<<(E_EDGES + 255) / 256, blk, 0, stream>>>(
        edge_src, edge_dst, rowptr_s, rowptr_t, col_s, col_t, E_EDGES);

    // ---- layer 1 ----
    mgemm_kernel<<<mg(NT), blk, 0, stream>>>(xt_b, wb_l1ts, DT, nullptr, nullptr, 0,
                                             nullptr, nullptr, Pt, NT, 0);
    gather_mean_kernel<<<(NT + 3) / 4, blk, 0, stream>>>(
        xs_b, rowptr_t, cnt_t, col_t, m_t, NT);
    gather_mean_kernel<<<(NS + 3) / 4, blk, 0, stream>>>(
        Pt, rowptr_s, cnt_s, col_s, m_s, NS);
    mgemm_kernel<<<mg(NT), blk, 0, stream>>>(m_t, wb_l1st, H, xt_b, wb_r1st, DT,
                                             nullptr, bl1_st, h1_t, NT, 1);
    mgemm_kernel<<<mg(NS), blk, 0, stream>>>(xs_b, wb_r1ts, DS, nullptr, nullptr, 0,
                                             m_s, bl1_ts, h1_s, NS, 1);

    // ---- layer 2 ----
    mgemm_kernel<<<mg(NT), blk, 0, stream>>>(h1_t, wb_l2ts, H, nullptr, nullptr, 0,
                                             nullptr, nullptr, Pt, NT, 0);
    gather_mean_kernel<<<(NT + 3) / 4, blk, 0, stream>>>(
        h1_s, rowptr_t, cnt_t, col_t, m_t, NT);
    gather_mean_kernel<<<(NS + 3) / 4, blk, 0, stream>>>(
        Pt, rowptr_s, cnt_s, col_s, m_s, NS);
    mgemm_kernel<<<mg(NT), blk, 0, stream>>>(m_t, wb_l2st, H, h1_t, wb_r2st, H,
                                             nullptr, bl2_st, h2_t, NT, 1);
    mgemm_kernel<<<mg(NS), blk, 0, stream>>>(h1_s, wb_r2ts, H, nullptr, nullptr, 0,
                                             m_s, bl2_ts, h2_s, NS, 1);

    // ---- decoder: U/V node potentials (fp16 out) + per-edge reduce ----
    mgemm_kernel<<<mg(NS), blk, 0, stream>>>(h2_s, wcb_s, H, nullptr, nullptr, 0,
                                             nullptr, bu, U, NS, 2);
    mgemm_kernel<<<mg(NT), blk, 0, stream>>>(h2_t, wcb_t, H, nullptr, nullptr, 0,
                                             nullptr, bv, V, NT, 2);
    edge_score_kernel<<<(EL_EDGES + 3) / 4, blk, 0, stream>>>(
        U, V, label_src, label_dst, Wd2, bd2, (float*)d_out, EL_EDGES);
}

// Round 8
// 994.150 us; speedup vs baseline: 12.6785x; 1.1232x over previous
//
#include <hip/hip_runtime.h>

// ---------------------------------------------------------------------------
// Hetero GraphSAGE (2 layers) + edge decoder.
// R1: CSR-gather aggregation. R4: algebraic restructure (U/V decoder split,
//     weight folding, project-before-aggregate). FLOP 1.23e11 -> 5.3e10.
// R5: bf16 MFMA GEMMs + bf16 activations. R6: fp16 U/V, fused CSR aux.
// R7 post-mortem: nontemporal col stores HURT (write-combining bypass).
// R8: two-pass LDS-binned CSR fill (pass A: LDS bins -> dense staged flush;
//     pass B: one block per bucket, LDS cursors, single-owner col writes).
//     Old fill: 148us, 108MB HBM writes for 6.4MB logical. Predicted ~14MB.
//     Gathers/edge_score: 16B/lane loads (32 lanes/row, 2 rows/wave).
// ---------------------------------------------------------------------------

constexpr int NS = 100000, NT = 20000;
constexpr int E_EDGES = 800000, EL_EDGES = 200000;
constexpr int DS = 256, DT = 128, H = 256;

// binning params: taxon dir (col_t, key=dst): 256 nodes/bucket -> 79 buckets
//                 sotu  dir (col_s, key=src): 1024 nodes/bucket -> 98 buckets
constexpr int NB_T = 79, SH_T = 8, VB_T = 17;    // pack: (dstlow<<17)|src
constexpr int NB_S = 98, SH_S = 10, VB_S = 15;   // pack: (srclow<<15)|dst
constexpr int BIN_CAP = 96, CHUNK = 2048;

typedef __attribute__((ext_vector_type(8))) short short8;
typedef __attribute__((ext_vector_type(4))) float float4v;
typedef __attribute__((ext_vector_type(8))) _Float16 half8v;
typedef unsigned short ushort_t;

__device__ __forceinline__ float bf2f(unsigned int u) {
    union { unsigned int i; float f; } x; x.i = u << 16; return x.f;
}
__device__ __forceinline__ unsigned short f2bf(float f) {
    union { float f; unsigned int i; } x; x.f = f;
    unsigned int r = x.i + 0x7FFFu + ((x.i >> 16) & 1u);   // RNE
    return (unsigned short)(r >> 16);
}

// --------------------------- MFMA GEMM -------------------------------------
// C[M,256] = op( A1@W1^T [+ A2@W2^T] [+ Add] [+ bias] )
// flags: 1 = relu, 2 = fp16 output (else bf16)
__global__ __launch_bounds__(256) void mgemm_kernel(
    const ushort_t* __restrict__ A1, const ushort_t* __restrict__ W1, int K1,
    const ushort_t* __restrict__ A2, const ushort_t* __restrict__ W2, int K2,
    const ushort_t* __restrict__ Add, const float* __restrict__ bias,
    void* __restrict__ Cout, int M, int flags)
{
    __shared__ ushort_t As[128][40];
    __shared__ ushort_t Bs[128][40];
    const int tid = threadIdx.x;
    const int row0 = blockIdx.x * 128, col0 = blockIdx.y * 128;
    const int wave = tid >> 6, lane = tid & 63;
    const int wrow = (wave >> 1) * 64, wcol = (wave & 1) * 64;
    const int m16 = lane & 15, quad = lane >> 4;
    const int sr = tid >> 2;
    const int skc = (tid & 3) * 8;

    float4v acc[4][4];
#pragma unroll
    for (int i = 0; i < 4; i++)
#pragma unroll
        for (int j = 0; j < 4; j++) acc[i][j] = (float4v){0.f, 0.f, 0.f, 0.f};

#pragma unroll 1
    for (int pass = 0; pass < 2; pass++) {
        const ushort_t* A = pass ? A2 : A1;
        const ushort_t* W = pass ? W2 : W1;
        const int K = pass ? K2 : K1;
        if (!A) break;
        const int gr0 = row0 + sr, gr1 = row0 + sr + 64;
        const bool ok0 = gr0 < M, ok1 = gr1 < M;
        for (int k0 = 0; k0 < K; k0 += 32) {
            uint4 a0 = make_uint4(0, 0, 0, 0), a1 = make_uint4(0, 0, 0, 0);
            if (ok0) a0 = *(const uint4*)&A[(size_t)gr0 * K + k0 + skc];
            if (ok1) a1 = *(const uint4*)&A[(size_t)gr1 * K + k0 + skc];
            uint4 b0 = *(const uint4*)&W[(size_t)(col0 + sr) * K + k0 + skc];
            uint4 b1 = *(const uint4*)&W[(size_t)(col0 + sr + 64) * K + k0 + skc];
            __syncthreads();
            *(uint4*)&As[sr][skc] = a0;
            *(uint4*)&As[sr + 64][skc] = a1;
            *(uint4*)&Bs[sr][skc] = b0;
            *(uint4*)&Bs[sr + 64][skc] = b1;
            __syncthreads();
            short8 af[4], bf[4];
#pragma unroll
            for (int i = 0; i < 4; i++)
                af[i] = *(const short8*)&As[wrow + i * 16 + m16][quad * 8];
#pragma unroll
            for (int j = 0; j < 4; j++)
                bf[j] = *(const short8*)&Bs[wcol + j * 16 + m16][quad * 8];
#pragma unroll
            for (int i = 0; i < 4; i++)
#pragma unroll
                for (int j = 0; j < 4; j++)
                    acc[i][j] = __builtin_amdgcn_mfma_f32_16x16x32_bf16(
                        af[i], bf[j], acc[i][j], 0, 0, 0);
        }
    }

    const bool relu = flags & 1, f16out = flags & 2;
#pragma unroll
    for (int i = 0; i < 4; i++) {
        const int rbase = row0 + wrow + i * 16 + quad * 4;
#pragma unroll
        for (int r = 0; r < 4; r++) {
            const int row = rbase + r;
            if (row >= M) continue;
#pragma unroll
            for (int j = 0; j < 4; j++) {
                const int col = col0 + wcol + j * 16 + m16;
                float v = acc[i][j][r];
                if (Add) v += bf2f((unsigned int)Add[(size_t)row * 256 + col]);
                if (bias) v += bias[col];
                if (relu) v = fmaxf(v, 0.f);
                if (f16out) ((_Float16*)Cout)[(size_t)row * 256 + col] = (_Float16)v;
                else ((ushort_t*)Cout)[(size_t)row * 256 + col] = f2bf(v);
            }
        }
    }
}

// --------------------- batched fp32 -> bf16 convert ------------------------
struct CvtJobs {
    const float* src[14];
    ushort_t* dst[14];
    int n4[14];
    int cnt;
};

__global__ __launch_bounds__(256) void cvt_kernel(CvtJobs jb, int total4)
{
    int t = blockIdx.x * blockDim.x + threadIdx.x;
    if (t >= total4) return;
    int idx = t;
    for (int k = 0; k < jb.cnt; k++) {
        if (idx < jb.n4[k]) {
            float4 v = ((const float4*)jb.src[k])[idx];
            uint2 o;
            o.x = (unsigned int)f2bf(v.x) | ((unsigned int)f2bf(v.y) << 16);
            o.y = (unsigned int)f2bf(v.z) | ((unsigned int)f2bf(v.w) << 16);
            *(uint2*)(jb.dst[k] + (size_t)idx * 4) = o;
            return;
        }
        idx -= jb.n4[k];
    }
}

// -------------- decoder weight folding (one fused kernel) ------------------
__global__ __launch_bounds__(256) void fold_kernel(
    const float* __restrict__ Wd1, const float* __restrict__ bd1,
    const float* __restrict__ Wlin_s, const float* __restrict__ blin_s,
    const float* __restrict__ Wlin_t, const float* __restrict__ blin_t,
    float* __restrict__ Wc_s, float* __restrict__ Wc_t,
    float* __restrict__ bu, float* __restrict__ bv)
{
    const int b = blockIdx.x, t = threadIdx.x;
    if (b < 256) {
        float s = 0.f;
        for (int k = 0; k < 256; k++) s += Wd1[b * 512 + k] * Wlin_s[k * 256 + t];
        Wc_s[b * 256 + t] = s;
    } else if (b < 512) {
        const int h = b - 256;
        float s = 0.f;
        for (int k = 0; k < 256; k++) s += Wd1[h * 512 + 256 + k] * Wlin_t[k * 256 + t];
        Wc_t[h * 256 + t] = s;
    } else {
        float su = 0.f, sv = 0.f;
        for (int k = 0; k < 256; k++) {
            su += Wd1[t * 512 + k] * blin_s[k];
            sv += Wd1[t * 512 + 256 + k] * blin_t[k];
        }
        bu[t] = bd1[t] + su;
        bv[t] = sv;
    }
}

// --------------------------- CSR build -------------------------------------
__global__ void count_kernel(const int* __restrict__ src, const int* __restrict__ dst,
                             int* __restrict__ cnt_s, int* __restrict__ cnt_t, int E)
{
    int e = blockIdx.x * blockDim.x + threadIdx.x;
    if (e < E) {
        atomicAdd(&cnt_s[src[e]], 1);
        atomicAdd(&cnt_t[dst[e]], 1);
    }
}

__global__ __launch_bounds__(256) void psum_kernel(
    const int* __restrict__ cnt_s, const int* __restrict__ cnt_t,
    int* __restrict__ bsum_s, int* __restrict__ bsum_t, int nbS)
{
    const bool isS = (int)blockIdx.x < nbS;
    const int blk = isS ? blockIdx.x : blockIdx.x - nbS;
    const int N = isS ? NS : NT;
    const int* cnt = isS ? cnt_s : cnt_t;
    int* bsum = isS ? bsum_s : bsum_t;
    __shared__ int sdata[256];
    const int t = threadIdx.x;
    const int base = blk * 1024;
    int s = 0;
    for (int i = t; i < 1024; i += 256) {
        int idx = base + i;
        s += (idx < N) ? cnt[idx] : 0;
    }
    sdata[t] = s; __syncthreads();
    for (int off = 128; off > 0; off >>= 1) {
        if (t < off) sdata[t] += sdata[t + off];
        __syncthreads();
    }
    if (t == 0) bsum[blk] = sdata[0];
}

__global__ void sbsum_kernel(int* __restrict__ bsum_s, int* __restrict__ bsum_t,
                             int nbS, int nbT)
{
    if (threadIdx.x != 0) return;
    int* b = blockIdx.x ? bsum_t : bsum_s;
    int nb = blockIdx.x ? nbT : nbS;
    int run = 0;
    for (int i = 0; i < nb; i++) { int v = b[i]; b[i] = run; run += v; }
}

// per-block exclusive scan -> rowptr[0..N], rowptr[N] = E
__global__ __launch_bounds__(256) void sblock_kernel(
    const int* __restrict__ cnt_s, const int* __restrict__ cnt_t,
    const int* __restrict__ bsum_s, const int* __restrict__ bsum_t,
    int* __restrict__ rowptr_s, int* __restrict__ rowptr_t, int nbS)
{
    const bool isS = (int)blockIdx.x < nbS;
    const int blk = isS ? blockIdx.x : blockIdx.x - nbS;
    const int N = isS ? NS : NT;
    const int* cnt = isS ? cnt_s : cnt_t;
    const int* bsum = isS ? bsum_s : bsum_t;
    int* rowptr = isS ? rowptr_s : rowptr_t;
    __shared__ int sc[256];
    const int t = threadIdx.x;
    const int base = blk * 1024 + t * 4;
    int v[4]; int s = 0;
#pragma unroll
    for (int j = 0; j < 4; j++) {
        int idx = base + j;
        v[j] = (idx < N) ? cnt[idx] : 0;
        s += v[j];
    }
    sc[t] = s; __syncthreads();
    for (int off = 1; off < 256; off <<= 1) {
        int add = (t >= off) ? sc[t - off] : 0;
        __syncthreads();
        sc[t] += add;
        __syncthreads();
    }
    int excl = sc[t] - s + bsum[blk];
#pragma unroll
    for (int j = 0; j < 4; j++) {
        int idx = base + j;
        if (idx < N) rowptr[idx] = excl;
        if (idx == N - 1) rowptr[N] = excl + v[j];
        excl += v[j];
    }
}

// init per-bucket staging cursors from rowptr at bucket boundaries
__global__ void binit_kernel(const int* __restrict__ rowptr_t,
                             const int* __restrict__ rowptr_s,
                             int* __restrict__ gcur_t, int* __restrict__ gcur_s)
{
    int t = threadIdx.x;
    if (t < NB_T) gcur_t[t] = rowptr_t[t << SH_T];
    if (t < NB_S) gcur_s[t] = rowptr_s[t << SH_S];
}

// pass A: LDS-bin edges by key bucket, flush dense to staged buffer
__global__ __launch_bounds__(256) void binA_kernel(
    const int* __restrict__ key, const int* __restrict__ val, int E,
    int nbins, int shift, int vbits,
    int* __restrict__ gcur, unsigned* __restrict__ stg)
{
    __shared__ unsigned bins[NB_S * BIN_CAP];   // 98*96*4B = 37.6 KB
    __shared__ int lcnt[NB_S], gbase[NB_S];
    const int tid = threadIdx.x;
    const int base = blockIdx.x * CHUNK;
    for (int i = tid; i < nbins; i += 256) lcnt[i] = 0;
    __syncthreads();
    const unsigned lowmask = (1u << shift) - 1u;
#pragma unroll
    for (int k = 0; k < CHUNK / 256; k++) {
        int e = base + k * 256 + tid;
        if (e < E) {
            int kk = key[e];
            int b = kk >> shift;
            unsigned pk = (((unsigned)kk & lowmask) << vbits) | (unsigned)val[e];
            int c = atomicAdd(&lcnt[b], 1);
            if (c < BIN_CAP) bins[b * BIN_CAP + c] = pk;
            else { int p = atomicAdd(&gcur[b], 1); stg[p] = pk; }
        }
    }
    __syncthreads();
    if (tid < nbins) gbase[tid] = atomicAdd(&gcur[tid], min(lcnt[tid], BIN_CAP));
    __syncthreads();
    for (int b = 0; b < nbins; b++) {
        int c = min(lcnt[b], BIN_CAP);
        for (int i = tid; i < c; i += 256) stg[gbase[b] + i] = bins[b * BIN_CAP + i];
    }
}

// pass B: one block per bucket; LDS cursors; single-owner col writes
__global__ __launch_bounds__(256) void binB_kernel(
    const unsigned* __restrict__ stg, const int* __restrict__ rowptr,
    int N, int node_per, int vbits, int* __restrict__ colout)
{
    __shared__ int cur[1024];
    const int tid = threadIdx.x;
    const int node0 = blockIdx.x * node_per;
    const int nn = min(node_per, N - node0);
    for (int i = tid; i < nn; i += 256) cur[i] = rowptr[node0 + i];
    const int estart = rowptr[node0];
    const int eend = rowptr[node0 + nn];
    __syncthreads();
    const unsigned vmask = (1u << vbits) - 1u;
    for (int i = estart + tid; i < eend; i += 256) {
        unsigned v = stg[i];
        int kl = (int)(v >> vbits);
        int pos = atomicAdd(&cur[kl], 1);
        colout[pos] = (int)(v & vmask);
    }
}

// ------------------- gather mean (bf16 rows, fp32 accum) -------------------
// 32 lanes per row (16B each), 2 nodes per wave, 8 nodes per block.
__global__ __launch_bounds__(256) void gather_mean_kernel(
    const ushort_t* __restrict__ X, const int* __restrict__ rowptr,
    const int* __restrict__ cnt, const int* __restrict__ col,
    ushort_t* __restrict__ out, int N)
{
    const int node = blockIdx.x * 8 + (threadIdx.x >> 5);
    const int c = (threadIdx.x & 31) * 8;
    if (node >= N) return;
    const int beg = rowptr[node];
    const int deg = cnt[node];
    const int end = beg + deg;
    float a[8] = {0, 0, 0, 0, 0, 0, 0, 0};
    float b[8] = {0, 0, 0, 0, 0, 0, 0, 0};
    int i = beg;
    for (; i + 1 < end; i += 2) {
        uint4 v = *(const uint4*)&X[(size_t)col[i] * 256 + c];
        uint4 w = *(const uint4*)&X[(size_t)col[i + 1] * 256 + c];
        a[0] += bf2f(v.x & 0xffff); a[1] += bf2f(v.x >> 16);
        a[2] += bf2f(v.y & 0xffff); a[3] += bf2f(v.y >> 16);
        a[4] += bf2f(v.z & 0xffff); a[5] += bf2f(v.z >> 16);
        a[6] += bf2f(v.w & 0xffff); a[7] += bf2f(v.w >> 16);
        b[0] += bf2f(w.x & 0xffff); b[1] += bf2f(w.x >> 16);
        b[2] += bf2f(w.y & 0xffff); b[3] += bf2f(w.y >> 16);
        b[4] += bf2f(w.z & 0xffff); b[5] += bf2f(w.z >> 16);
        b[6] += bf2f(w.w & 0xffff); b[7] += bf2f(w.w >> 16);
    }
    if (i < end) {
        uint4 v = *(const uint4*)&X[(size_t)col[i] * 256 + c];
        a[0] += bf2f(v.x & 0xffff); a[1] += bf2f(v.x >> 16);
        a[2] += bf2f(v.y & 0xffff); a[3] += bf2f(v.y >> 16);
        a[4] += bf2f(v.z & 0xffff); a[5] += bf2f(v.z >> 16);
        a[6] += bf2f(v.w & 0xffff); a[7] += bf2f(v.w >> 16);
    }
    float inv = 1.f / fmaxf((float)deg, 1.f);
    uint4 o;
    o.x = (unsigned int)f2bf((a[0] + b[0]) * inv) | ((unsigned int)f2bf((a[1] + b[1]) * inv) << 16);
    o.y = (unsigned int)f2bf((a[2] + b[2]) * inv) | ((unsigned int)f2bf((a[3] + b[3]) * inv) << 16);
    o.z = (unsigned int)f2bf((a[4] + b[4]) * inv) | ((unsigned int)f2bf((a[5] + b[5]) * inv) << 16);
    o.w = (unsigned int)f2bf((a[6] + b[6]) * inv) | ((unsigned int)f2bf((a[7] + b[7]) * inv) << 16);
    *(uint4*)&out[(size_t)node * 256 + c] = o;
}

// ------------------------- per-edge score (fp16 U/V) -----------------------
// 32 lanes per edge (16B each), 2 edges per wave, 8 per block.
__global__ __launch_bounds__(256) void edge_score_kernel(
    const _Float16* __restrict__ U, const _Float16* __restrict__ V,
    const int* __restrict__ ls, const int* __restrict__ ld,
    const float* __restrict__ Wd2, const float* __restrict__ bd2,
    float* __restrict__ out, int EL)
{
    const int lane = threadIdx.x & 63;
    const int l32 = lane & 31;
    const int e = blockIdx.x * 8 + (threadIdx.x >> 5);
    if (e >= EL) return;
    const int c = l32 * 8;
    half8v u = *(const half8v*)&U[(size_t)ls[e] * 256 + c];
    half8v v = *(const half8v*)&V[(size_t)ld[e] * 256 + c];
    float4 w0 = *(const float4*)&Wd2[c];
    float4 w1 = *(const float4*)&Wd2[c + 4];
    float s = fmaxf((float)u[0] + (float)v[0], 0.f) * w0.x
            + fmaxf((float)u[1] + (float)v[1], 0.f) * w0.y
            + fmaxf((float)u[2] + (float)v[2], 0.f) * w0.z
            + fmaxf((float)u[3] + (float)v[3], 0.f) * w0.w
            + fmaxf((float)u[4] + (float)v[4], 0.f) * w1.x
            + fmaxf((float)u[5] + (float)v[5], 0.f) * w1.y
            + fmaxf((float)u[6] + (float)v[6], 0.f) * w1.z
            + fmaxf((float)u[7] + (float)v[7], 0.f) * w1.w;
#pragma unroll
    for (int m = 16; m >= 1; m >>= 1) s += __shfl_xor(s, m, 64);
    if (l32 == 0) out[e] = s + bd2[0];
}

// ---------------------------------------------------------------------------
extern "C" void kernel_launch(void* const* d_in, const int* in_sizes, int n_in,
                              void* d_out, int out_size, void* d_ws, size_t ws_size,
                              hipStream_t stream)
{
    const float* x_sotu  = (const float*)d_in[0];
    const float* x_taxon = (const float*)d_in[1];
    const int* edge_src  = (const int*)d_in[2];
    const int* edge_dst  = (const int*)d_in[3];
    const int* label_src = (const int*)d_in[4];
    const int* label_dst = (const int*)d_in[5];
    const float* Wl1_st = (const float*)d_in[6];
    const float* bl1_st = (const float*)d_in[7];
    const float* Wr1_st = (const float*)d_in[8];
    const float* Wl1_ts = (const float*)d_in[9];
    const float* bl1_ts = (const float*)d_in[10];
    const float* Wr1_ts = (const float*)d_in[11];
    const float* Wl2_st = (const float*)d_in[12];
    const float* bl2_st = (const float*)d_in[13];
    const float* Wr2_st = (const float*)d_in[14];
    const float* Wl2_ts = (const float*)d_in[15];
    const float* bl2_ts = (const float*)d_in[16];
    const float* Wr2_ts = (const float*)d_in[17];
    const float* Wlin_s = (const float*)d_in[18];
    const float* blin_s = (const float*)d_in[19];
    const float* Wlin_t = (const float*)d_in[20];
    const float* blin_t = (const float*)d_in[21];
    const float* Wd1 = (const float*)d_in[22];
    const float* bd1 = (const float*)d_in[23];
    const float* Wd2 = (const float*)d_in[24];
    const float* bd2 = (const float*)d_in[25];

    // -------- workspace layout --------
    int* wi = (int*)d_ws;
    size_t io = 0;
    int* cnt_s   = wi + io; io += NS;
    int* cnt_t   = wi + io; io += NT;
    int* rowptr_s = wi + io; io += NS + 8;
    int* rowptr_t = wi + io; io += NT + 8;
    int* col_s   = wi + io; io += E_EDGES;
    int* col_t   = wi + io; io += E_EDGES;
    unsigned* stg_s = (unsigned*)(wi + io); io += E_EDGES;
    unsigned* stg_t = (unsigned*)(wi + io); io += E_EDGES;
    int* bsum_s  = wi + io; io += 128;
    int* bsum_t  = wi + io; io += 128;
    int* gcur_t  = wi + io; io += 128;
    int* gcur_s  = wi + io; io += 128;
    io = (io + 63) & ~(size_t)63;           // 256B-align

    ushort_t* wb = (ushort_t*)(wi + io);
    size_t bo = 0;
    ushort_t* m_s  = wb + bo; bo += (size_t)NS * H;   // U (fp16) overlays m_s
    ushort_t* h1_s = wb + bo; bo += (size_t)NS * H;
    ushort_t* m_t  = wb + bo; bo += (size_t)NT * H;   // V (fp16) overlays m_t
    ushort_t* h1_t = wb + bo; bo += (size_t)NT * H;
    ushort_t* h2_s = wb + bo; bo += (size_t)NS * H;
    ushort_t* h2_t = wb + bo; bo += (size_t)NT * H;
    ushort_t* xs_b = wb + bo; bo += (size_t)NS * DS;
    ushort_t* xt_b = wb + bo; bo += (size_t)NT * DT;
    ushort_t* Pt   = wb + bo; bo += (size_t)NT * H;
    ushort_t* wb_l1st = wb + bo; bo += H * DS;
    ushort_t* wb_r1st = wb + bo; bo += H * DT;
    ushort_t* wb_l1ts = wb + bo; bo += H * DT;
    ushort_t* wb_r1ts = wb + bo; bo += H * DS;
    ushort_t* wb_l2st = wb + bo; bo += H * H;
    ushort_t* wb_r2st = wb + bo; bo += H * H;
    ushort_t* wb_l2ts = wb + bo; bo += H * H;
    ushort_t* wb_r2ts = wb + bo; bo += H * H;
    ushort_t* wcb_s   = wb + bo; bo += H * H;
    ushort_t* wcb_t   = wb + bo; bo += H * H;
    bo = (bo + 7) & ~(size_t)7;

    float* wf = (float*)(wb + bo);
    size_t fo = 0;
    float* Wc_s = wf + fo; fo += H * H;
    float* Wc_t = wf + fo; fo += H * H;
    float* bu   = wf + fo; fo += 256;
    float* bv   = wf + fo; fo += 256;

    _Float16* U = (_Float16*)m_s;
    _Float16* V = (_Float16*)m_t;

    const dim3 blk(256);
    auto mg = [](int M) { return dim3((M + 127) / 128, 2); };
    const int nbS = (NS + 1023) / 1024;   // 98
    const int nbT = (NT + 1023) / 1024;   // 20
    const int nA = (E_EDGES + CHUNK - 1) / CHUNK;   // 391

    // ---- decoder weight folding ----
    fold_kernel<<<513, blk, 0, stream>>>(Wd1, bd1, Wlin_s, blin_s, Wlin_t, blin_t,
                                         Wc_s, Wc_t, bu, bv);

    // ---- batched fp32->bf16 conversion ----
    {
        CvtJobs jb; int c = 0, total4 = 0;
        auto addj = [&](const float* s, ushort_t* d, int n) {
            jb.src[c] = s; jb.dst[c] = d; jb.n4[c] = n / 4; total4 += n / 4; c++;
        };
        addj(x_sotu, xs_b, NS * DS);
        addj(x_taxon, xt_b, NT * DT);
        addj(Wl1_st, wb_l1st, H * DS);
        addj(Wr1_st, wb_r1st, H * DT);
        addj(Wl1_ts, wb_l1ts, H * DT);
        addj(Wr1_ts, wb_r1ts, H * DS);
        addj(Wl2_st, wb_l2st, H * H);
        addj(Wr2_st, wb_r2st, H * H);
        addj(Wl2_ts, wb_l2ts, H * H);
        addj(Wr2_ts, wb_r2ts, H * H);
        addj(Wc_s, wcb_s, H * H);
        addj(Wc_t, wcb_t, H * H);
        jb.cnt = c;
        cvt_kernel<<<(total4 + 255) / 256, blk, 0, stream>>>(jb, total4);
    }

    // ---- CSR build: count -> scan -> binned two-pass fill ----
    hipMemsetAsync(cnt_s, 0, (size_t)(NS + NT) * sizeof(int), stream);
    count_kernel<<<(E_EDGES + 255) / 256, blk, 0, stream>>>(edge_src, edge_dst,
                                                            cnt_s, cnt_t, E_EDGES);
    psum_kernel<<<nbS + nbT, blk, 0, stream>>>(cnt_s, cnt_t, bsum_s, bsum_t, nbS);
    sbsum_kernel<<<2, 64, 0, stream>>>(bsum_s, bsum_t, nbS, nbT);
    sblock_kernel<<<nbS + nbT, blk, 0, stream>>>(cnt_s, cnt_t, bsum_s, bsum_t,
                                                 rowptr_s, rowptr_t, nbS);
    binit_kernel<<<1, blk, 0, stream>>>(rowptr_t, rowptr_s, gcur_t, gcur_s);
    binA_kernel<<<nA, blk, 0, stream>>>(edge_dst, edge_src, E_EDGES,
                                        NB_T, SH_T, VB_T, gcur_t, stg_t);
    binA_kernel<<<nA, blk, 0, stream>>>(edge_src, edge_dst, E_EDGES,
                                        NB_S, SH_S, VB_S, gcur_s, stg_s);
    binB_kernel<<<NB_T, blk, 0, stream>>>(stg_t, rowptr_t, NT, 1 << SH_T, VB_T, col_t);
    binB_kernel<<<NB_S, blk, 0, stream>>>(stg_s, rowptr_s, NS, 1 << SH_S, VB_S, col_s);

    // ---- layer 1 ----
    mgemm_kernel<<<mg(NT), blk, 0, stream>>>(xt_b, wb_l1ts, DT, nullptr, nullptr, 0,
                                             nullptr, nullptr, Pt, NT, 0);
    gather_mean_kernel<<<(NT + 7) / 8, blk, 0, stream>>>(
        xs_b, rowptr_t, cnt_t, col_t, m_t, NT);
    gather_mean_kernel<<<(NS + 7) / 8, blk, 0, stream>>>(
        Pt, rowptr_s, cnt_s, col_s, m_s, NS);
    mgemm_kernel<<<mg(NT), blk, 0, stream>>>(m_t, wb_l1st, H, xt_b, wb_r1st, DT,
                                             nullptr, bl1_st, h1_t, NT, 1);
    mgemm_kernel<<<mg(NS), blk, 0, stream>>>(xs_b, wb_r1ts, DS, nullptr, nullptr, 0,
                                             m_s, bl1_ts, h1_s, NS, 1);

    // ---- layer 2 ----
    mgemm_kernel<<<mg(NT), blk, 0, stream>>>(h1_t, wb_l2ts, H, nullptr, nullptr, 0,
                                             nullptr, nullptr, Pt, NT, 0);
    gather_mean_kernel<<<(NT + 7) / 8, blk, 0, stream>>>(
        h1_s, rowptr_t, cnt_t, col_t, m_t, NT);
    gather_mean_kernel<<<(NS + 7) / 8, blk, 0, stream>>>(
        Pt, rowptr_s, cnt_s, col_s, m_s, NS);
    mgemm_kernel<<<mg(NT), blk, 0, stream>>>(m_t, wb_l2st, H, h1_t, wb_r2st, H,
                                             nullptr, bl2_st, h2_t, NT, 1);
    mgemm_kernel<<<mg(NS), blk, 0, stream>>>(h1_s, wb_r2ts, H, nullptr, nullptr, 0,
                                             m_s, bl2_ts, h2_s, NS, 1);

    // ---- decoder: U/V node potentials (fp16 out) + per-edge reduce ----
    mgemm_kernel<<<mg(NS), blk, 0, stream>>>(h2_s, wcb_s, H, nullptr, nullptr, 0,
                                             nullptr, bu, U, NS, 2);
    mgemm_kernel<<<mg(NT), blk, 0, stream>>>(h2_t, wcb_t, H, nullptr, nullptr, 0,
                                             nullptr, bv, V, NT, 2);
    edge_score_kernel<<<(EL_EDGES + 7) / 8, blk, 0, stream>>>(
        U, V, label_src, label_dst, Wd2, bd2, (float*)d_out, EL_EDGES);
}